// Round 10
// baseline (621.377 us; speedup 1.0000x reference)
//
#include <hip/hip_runtime.h>
#include <math.h>

#define HH 128   // hidden dim (both layers) == input F
#define PS 16    // pool slices per graph

__device__ __forceinline__ float dot4(float4 a, float4 b){
  return a.x*b.x + a.y*b.y + a.z*b.z + a.w*b.w;
}

// fast sigmoid: v_rcp_f32 instead of full IEEE divide (~6 instrs -> 1)
__device__ __forceinline__ float sigf(float t){
  return __builtin_amdgcn_rcpf(1.f + __expf(-t));
}

// ---------------------------------------------------------------------------
// GEMM v5 (round-7 exact layout): BM=64, BK=64, stride-68 LDS rows,
// measured 0 bank conflicts, VALUBusy ~67%, 111 us/dispatch.
// m = blockIdx.x & 3 selects {K,Q,V,skip}; consecutive blocks share the
// X row-tile -> X stays L2/L3-hot.
// ---------------------------------------------------------------------------
template<bool RELU>
__global__ __launch_bounds__(256) void gemm_tile(
    const float* __restrict__ X,
    const float* __restrict__ Wk, const float* __restrict__ bk,
    const float* __restrict__ Wq, const float* __restrict__ bq,
    const float* __restrict__ Wv, const float* __restrict__ bv,
    const float* __restrict__ Ws, const float* __restrict__ bs,
    float* __restrict__ Ko, float* __restrict__ Qo,
    float* __restrict__ Vo, float* __restrict__ So, int n)
{
  __shared__ float sX[64 * 68];    // 17.4 KB
  __shared__ float sW[128 * 68];   // 34.8 KB

  const int m = blockIdx.x & 3;
  const float* W; const float* B; float* D;
  if (m == 0){ W = Wk; B = bk; D = Ko; }
  else if (m == 1){ W = Wq; B = bq; D = Qo; }
  else if (m == 2){ W = Wv; B = bv; D = Vo; }
  else { W = Ws; B = bs; D = So; }

  const int tid = threadIdx.x;
  const int tx = tid & 15;       // col group: cols tx + 16j, j=0..7
  const int ty = tid >> 4;       // row group: rows ty + 16i, i=0..3
  const int row0 = (blockIdx.x >> 2) * 64;

  float acc[4][8];
#pragma unroll
  for (int i = 0; i < 4; ++i)
#pragma unroll
    for (int j = 0; j < 8; ++j) acc[i][j] = 0.f;

  for (int kc = 0; kc < 2; ++kc){
    const int k0q = kc * 16;  // float4 offset of this k-chunk
    // stage X chunk: 64 rows x 16 float4
    for (int fi = tid; fi < 64 * 16; fi += 256){
      int r = fi >> 4, kq = fi & 15;
      int gr = row0 + r;
      float4 v = make_float4(0.f, 0.f, 0.f, 0.f);
      if (gr < n){
        v = ((const float4*)X)[(size_t)gr * 32 + k0q + kq];
        if (RELU){
          v.x = fmaxf(v.x, 0.f); v.y = fmaxf(v.y, 0.f);
          v.z = fmaxf(v.z, 0.f); v.w = fmaxf(v.w, 0.f);
        }
      }
      *(float4*)&sX[r * 68 + kq * 4] = v;
    }
    // stage W chunk: 128 cols x 16 float4
    for (int fi = tid; fi < 128 * 16; fi += 256){
      int c = fi >> 4, kq = fi & 15;
      float4 v = ((const float4*)W)[c * 32 + k0q + kq];
      *(float4*)&sW[c * 68 + kq * 4] = v;
    }
    __syncthreads();

    for (int k = 0; k < 64; k += 4){
      float4 a[4], w[8];
#pragma unroll
      for (int i = 0; i < 4; ++i)
        a[i] = *(const float4*)&sX[(ty + 16 * i) * 68 + k];
#pragma unroll
      for (int j = 0; j < 8; ++j)
        w[j] = *(const float4*)&sW[(tx + 16 * j) * 68 + k];
#pragma unroll
      for (int i = 0; i < 4; ++i)
#pragma unroll
        for (int j = 0; j < 8; ++j){
          float s = acc[i][j];
          s = fmaf(a[i].x, w[j].x, s);
          s = fmaf(a[i].y, w[j].y, s);
          s = fmaf(a[i].z, w[j].z, s);
          s = fmaf(a[i].w, w[j].w, s);
          acc[i][j] = s;
        }
    }
    __syncthreads();
  }

#pragma unroll
  for (int i = 0; i < 4; ++i){
    int gr = row0 + ty + 16 * i;
    if (gr < n){
#pragma unroll
      for (int j = 0; j < 8; ++j){
        int c = tx + 16 * j;
        D[(size_t)gr * HH + c] = acc[i][j] + B[c];
      }
    }
  }
}

// ---------------------------------------------------------------------------
// CSR build
// ---------------------------------------------------------------------------
__global__ void zero_int(int* __restrict__ p, int n){
  int i = blockIdx.x * blockDim.x + threadIdx.x;
  if (i < n) p[i] = 0;
}

__global__ void hist_dst(const int* __restrict__ ei, int E, int* __restrict__ cnt){
  int e = blockIdx.x * blockDim.x + threadIdx.x;
  if (e < E) atomicAdd(&cnt[ei[E + e]], 1);
}

__global__ __launch_bounds__(256) void scan1(const int* __restrict__ cnt, int n,
                                             int* __restrict__ excl, int* __restrict__ bsum){
  __shared__ int s[256];
  int t = threadIdx.x;
  int i = blockIdx.x * 256 + t;
  int v = (i < n) ? cnt[i] : 0;
  s[t] = v;
  __syncthreads();
  for (int off = 1; off < 256; off <<= 1){
    int u = (t >= off) ? s[t - off] : 0;
    __syncthreads();
    s[t] += u;
    __syncthreads();
  }
  if (i < n) excl[i] = s[t] - v;
  if (t == 255) bsum[blockIdx.x] = s[255];
}

__global__ __launch_bounds__(256) void scan2(int* __restrict__ bsum, int nb){
  __shared__ int s[256];
  int t = threadIdx.x;
  int v = (t < nb) ? bsum[t] : 0;
  s[t] = v;
  __syncthreads();
  for (int off = 1; off < 256; off <<= 1){
    int u = (t >= off) ? s[t - off] : 0;
    __syncthreads();
    s[t] += u;
    __syncthreads();
  }
  if (t < nb) bsum[t] = s[t] - v;
}

__global__ void scan3(int* __restrict__ row_start, const int* __restrict__ bsum,
                      int n, int E, int* __restrict__ cursor){
  int i = blockIdx.x * blockDim.x + threadIdx.x;
  if (i < n){
    int v = row_start[i] + bsum[i >> 8];
    row_start[i] = v;
    cursor[i] = v;
  }
  if (i == n) row_start[n] = E;
}

__global__ void scatter_src(const int* __restrict__ ei, int E,
                            int* __restrict__ cursor, int* __restrict__ csr_src){
  int e = blockIdx.x * blockDim.x + threadIdx.x;
  if (e < E){
    int d = ei[E + e];
    int pos = atomicAdd(&cursor[d], 1);
    csr_src[pos] = ei[e];
  }
}

// ---------------------------------------------------------------------------
// Node-centric aggregate: one wave per dst node, float2 per lane.
// This round: sigmoid via v_rcp_f32 (sigf) + edge loop unrolled x4
// for deeper memory-level parallelism on the Q/V row gathers.
// ---------------------------------------------------------------------------
__global__ __launch_bounds__(256) void node_agg(
    const float* __restrict__ Kx, const float* __restrict__ Qx,
    const float* __restrict__ Vx, const float* __restrict__ Sx,
    const int* __restrict__ row_start, const int* __restrict__ csr_src,
    int n, float* __restrict__ H)
{
  int w = blockIdx.x * 4 + (threadIdx.x >> 6);
  w = __builtin_amdgcn_readfirstlane(w);
  if (w >= n) return;
  int lane = threadIdx.x & 63;

  float2 kd = ((const float2*)(Kx + (size_t)w * HH))[lane];
  float ax = 0.f, ay = 0.f;
  int j = row_start[w];
  const int jend = row_start[w + 1];

  for (; j + 3 < jend; j += 4){
    int s0 = csr_src[j],     s1 = csr_src[j + 1];
    int s2 = csr_src[j + 2], s3 = csr_src[j + 3];
    float2 q0 = ((const float2*)(Qx + (size_t)s0 * HH))[lane];
    float2 v0 = ((const float2*)(Vx + (size_t)s0 * HH))[lane];
    float2 q1 = ((const float2*)(Qx + (size_t)s1 * HH))[lane];
    float2 v1 = ((const float2*)(Vx + (size_t)s1 * HH))[lane];
    float2 q2 = ((const float2*)(Qx + (size_t)s2 * HH))[lane];
    float2 v2 = ((const float2*)(Vx + (size_t)s2 * HH))[lane];
    float2 q3 = ((const float2*)(Qx + (size_t)s3 * HH))[lane];
    float2 v3 = ((const float2*)(Vx + (size_t)s3 * HH))[lane];
    ax = fmaf(sigf(kd.x + q0.x), v0.x, ax);
    ay = fmaf(sigf(kd.y + q0.y), v0.y, ay);
    ax = fmaf(sigf(kd.x + q1.x), v1.x, ax);
    ay = fmaf(sigf(kd.y + q1.y), v1.y, ay);
    ax = fmaf(sigf(kd.x + q2.x), v2.x, ax);
    ay = fmaf(sigf(kd.y + q2.y), v2.y, ay);
    ax = fmaf(sigf(kd.x + q3.x), v3.x, ax);
    ay = fmaf(sigf(kd.y + q3.y), v3.y, ay);
  }
  for (; j < jend; ++j){
    int sA = csr_src[j];
    float2 qa = ((const float2*)(Qx + (size_t)sA * HH))[lane];
    float2 va = ((const float2*)(Vx + (size_t)sA * HH))[lane];
    ax = fmaf(sigf(kd.x + qa.x), va.x, ax);
    ay = fmaf(sigf(kd.y + qa.y), va.y, ay);
  }
  float2 sk = ((const float2*)(Sx + (size_t)w * HH))[lane];
  float2 o; o.x = ax + sk.x; o.y = ay + sk.y;
  ((float2*)(H + (size_t)w * HH))[lane] = o;
}

// ---------------------------------------------------------------------------
// Pool, two-phase.
// ---------------------------------------------------------------------------
__global__ __launch_bounds__(256) void pool_partial(
    const float* __restrict__ Hn, const int* __restrict__ batch,
    int n, float* __restrict__ pmax, float* __restrict__ psum)
{
  int g = blockIdx.x;
  int s = blockIdx.y;
  int lo = 0, hi = n;
  while (lo < hi){ int mid = (lo + hi) >> 1; if (batch[mid] < g) lo = mid + 1; else hi = mid; }
  int s0 = lo;
  lo = s0; hi = n;
  while (lo < hi){ int mid = (lo + hi) >> 1; if (batch[mid] < g + 1) lo = mid + 1; else hi = mid; }
  int e0 = lo;

  int len = e0 - s0;
  int a0 = s0 + (int)(((long long)len * s) / PS);
  int a1 = s0 + (int)(((long long)len * (s + 1)) / PS);

  int t = threadIdx.x;
  int f = t & 127;
  int half = t >> 7;
  float mx = -INFINITY;
  float sm = 0.f;
  for (int i = a0 + half; i < a1; i += 2){
    float v = Hn[(size_t)i * HH + f];
    mx = fmaxf(mx, v);
    sm += v;
  }
  __shared__ float smx[256], ssm[256];
  smx[t] = mx; ssm[t] = sm;
  __syncthreads();
  if (half == 0){
    mx = fmaxf(mx, smx[t + 128]);
    sm += ssm[t + 128];
    size_t o = ((size_t)g * PS + s) * 128 + f;
    pmax[o] = mx;
    psum[o] = sm;
  }
}

__global__ __launch_bounds__(128) void pool_reduce(
    const float* __restrict__ pmax, const float* __restrict__ psum,
    const int* __restrict__ batch, int n, float* __restrict__ Fp)
{
  int g = blockIdx.x;
  int f = threadIdx.x;
  int lo = 0, hi = n;
  while (lo < hi){ int mid = (lo + hi) >> 1; if (batch[mid] < g) lo = mid + 1; else hi = mid; }
  int s0 = lo;
  lo = s0; hi = n;
  while (lo < hi){ int mid = (lo + hi) >> 1; if (batch[mid] < g + 1) lo = mid + 1; else hi = mid; }
  int cnt = lo - s0;

  float mx = -INFINITY, sm = 0.f;
#pragma unroll
  for (int s = 0; s < PS; ++s){
    size_t o = ((size_t)g * PS + s) * 128 + f;
    mx = fmaxf(mx, pmax[o]);
    sm += psum[o];
  }
  float mean = sm / fmaxf((float)cnt, 1.0f);
  Fp[(size_t)g * 256 + f]       = mx;
  Fp[(size_t)g * 256 + 128 + f] = mean;
}

// ---------------------------------------------------------------------------
// MLP head (parallel)
// ---------------------------------------------------------------------------
__global__ __launch_bounds__(256) void head_gemm1(
    const float* __restrict__ Fp, const float* __restrict__ W1,
    const float* __restrict__ b1, float* __restrict__ A1)
{
  int idx = blockIdx.x * 256 + threadIdx.x;
  int r = idx >> 7, c = idx & 127;
  const float4* f4 = (const float4*)(Fp + r * 256);
  const float4* w4 = (const float4*)(W1 + c * 256);
  float acc = b1[c];
#pragma unroll
  for (int k = 0; k < 64; ++k) acc += dot4(f4[k], w4[k]);
  A1[idx] = acc;
}

__global__ __launch_bounds__(256) void head_bn_relu1(
    const float* __restrict__ A1, const float* __restrict__ g1,
    const float* __restrict__ be1, float* __restrict__ H1n)
{
  __shared__ float sMS[256];
  int t = threadIdx.x;
  if (t < 128){
    float m = 0.f, m2 = 0.f;
    for (int r = 0; r < 64; ++r){ float v = A1[r * 128 + t]; m += v; m2 += v * v; }
    m *= (1.f / 64.f); m2 *= (1.f / 64.f);
    float var = m2 - m * m;
    sMS[t] = m;
    sMS[128 + t] = g1[t] * rsqrtf(var + 1e-5f);
  }
  __syncthreads();
  for (int i = t; i < 64 * 128; i += 256){
    int c = i & 127;
    float v = (A1[i] - sMS[c]) * sMS[128 + c] + be1[c];
    H1n[i] = fmaxf(v, 0.f);
  }
}

__global__ __launch_bounds__(256) void head_gemm2(
    const float* __restrict__ H1n, const float* __restrict__ W2,
    const float* __restrict__ b2, float* __restrict__ A2)
{
  int idx = blockIdx.x * 256 + threadIdx.x;
  int r = idx >> 6, c = idx & 63;
  const float4* f4 = (const float4*)(H1n + r * 128);
  const float4* w4 = (const float4*)(W2 + c * 128);
  float acc = b2[c];
#pragma unroll
  for (int k = 0; k < 32; ++k) acc += dot4(f4[k], w4[k]);
  A2[idx] = acc;
}

__global__ __launch_bounds__(256) void head_tail(
    const float* __restrict__ A2, const float* __restrict__ g2,
    const float* __restrict__ be2, const float* __restrict__ W3,
    const float* __restrict__ b3, float* __restrict__ out)
{
  __shared__ float sH[64 * 64];
  __shared__ float sMS[128];
  int t = threadIdx.x;
  for (int i = t; i < 64 * 64 / 4; i += 256)
    ((float4*)sH)[i] = ((const float4*)A2)[i];
  __syncthreads();
  if (t < 64){
    float m = 0.f, m2 = 0.f;
    for (int r = 0; r < 64; ++r){ float v = sH[r * 64 + t]; m += v; m2 += v * v; }
    m *= (1.f / 64.f); m2 *= (1.f / 64.f);
    float var = m2 - m * m;
    sMS[t] = m;
    sMS[64 + t] = g2[t] * rsqrtf(var + 1e-5f);
  }
  __syncthreads();
  for (int i = t; i < 64 * 64; i += 256){
    int c = i & 63;
    float v = (sH[i] - sMS[c]) * sMS[64 + c] + be2[c];
    sH[i] = fmaxf(v, 0.f);
  }
  __syncthreads();
  if (t < 64){
    float acc = b3[0];
#pragma unroll
    for (int k = 0; k < 64; ++k) acc += sH[t * 64 + k] * W3[k];
    out[t] = acc;
  }
}

// ---------------------------------------------------------------------------
extern "C" void kernel_launch(void* const* d_in, const int* in_sizes, int n_in,
                              void* d_out, int out_size, void* d_ws, size_t ws_size,
                              hipStream_t stream)
{
  const float* x     = (const float*)d_in[0];
  const int*   ei    = (const int*)d_in[1];
  const int*   batch = (const int*)d_in[2];

  const float* l0Wk = (const float*)d_in[3];  const float* l0bk = (const float*)d_in[4];
  const float* l0Wq = (const float*)d_in[5];  const float* l0bq = (const float*)d_in[6];
  const float* l0Wv = (const float*)d_in[7];  const float* l0bv = (const float*)d_in[8];
  const float* l0Ws = (const float*)d_in[9];  const float* l0bs = (const float*)d_in[10];
  const float* l1Wk = (const float*)d_in[11]; const float* l1bk = (const float*)d_in[12];
  const float* l1Wq = (const float*)d_in[13]; const float* l1bq = (const float*)d_in[14];
  const float* l1Wv = (const float*)d_in[15]; const float* l1bv = (const float*)d_in[16];
  const float* l1Ws = (const float*)d_in[17]; const float* l1bs = (const float*)d_in[18];

  const float* W1  = (const float*)d_in[19]; const float* b1  = (const float*)d_in[20];
  const float* g1  = (const float*)d_in[21]; const float* be1 = (const float*)d_in[22];
  const float* W2  = (const float*)d_in[23]; const float* b2  = (const float*)d_in[24];
  const float* g2  = (const float*)d_in[25]; const float* be2 = (const float*)d_in[26];
  const float* W3  = (const float*)d_in[27]; const float* b3  = (const float*)d_in[28];

  const int N = in_sizes[0] / HH;
  const int E = in_sizes[1] / 2;
  const int G = out_size;
  const size_t NH = (size_t)N * HH;

  float* ws = (float*)d_ws;
  float* K  = ws;
  float* Q  = K  + NH;
  float* V  = Q  + NH;
  float* H0 = V  + NH;
  float* H1 = H0 + NH;
  float* Fp = H1 + NH;                          // G*256
  float* A1  = Fp + (size_t)G * 256;            // 64*128
  float* H1n = A1 + 64 * 128;
  float* A2  = H1n + 64 * 128;                  // 64*64
  float* pmax = A2 + 64 * 64;                   // G*PS*128
  float* psum = pmax + (size_t)G * PS * 128;    // G*PS*128
  int* ip        = (int*)(psum + (size_t)G * PS * 128);
  int* row_start = ip;                 // N+1
  int* cursor    = row_start + (N + 1);
  int* cnt       = cursor + N;
  int* csr_src   = cnt + N;            // E
  int* bsum      = csr_src + E;        // 256

  const int nb   = (N + 255) / 256;
  const int ebl  = (E + 255) / 256;
  const int gemm_blocks = ((N + 63) / 64) * 4;   // 4 matrices interleaved
  const int agg_blocks = (N + 3) / 4;

  // --- CSR build ---
  zero_int<<<nb, 256, 0, stream>>>(cnt, N);
  hist_dst<<<ebl, 256, 0, stream>>>(ei, E, cnt);
  scan1<<<nb, 256, 0, stream>>>(cnt, N, row_start, bsum);
  scan2<<<1, 256, 0, stream>>>(bsum, nb);
  scan3<<<(N + 256) / 256, 256, 0, stream>>>(row_start, bsum, N, E, cursor);
  scatter_src<<<ebl, 256, 0, stream>>>(ei, E, cursor, csr_src);

  // --- Layer 0 ---
  gemm_tile<false><<<gemm_blocks, 256, 0, stream>>>(
      x, l0Wk, l0bk, l0Wq, l0bq, l0Wv, l0bv, l0Ws, l0bs, K, Q, V, H0, N);
  node_agg<<<agg_blocks, 256, 0, stream>>>(K, Q, V, H0, row_start, csr_src, N, H0);

  // --- Layer 1 ---
  gemm_tile<true><<<gemm_blocks, 256, 0, stream>>>(
      H0, l1Wk, l1bk, l1Wq, l1bq, l1Wv, l1bv, l1Ws, l1bs, K, Q, V, H1, N);
  node_agg<<<agg_blocks, 256, 0, stream>>>(K, Q, V, H1, row_start, csr_src, N, H1);

  // --- Pool (two-phase) + head ---
  pool_partial<<<dim3(G, PS), 256, 0, stream>>>(H1, batch, N, pmax, psum);
  pool_reduce<<<G, 128, 0, stream>>>(pmax, psum, batch, N, Fp);
  head_gemm1<<<32, 256, 0, stream>>>(Fp, W1, b1, A1);
  head_bn_relu1<<<1, 256, 0, stream>>>(A1, g1, be1, H1n);
  head_gemm2<<<16, 256, 0, stream>>>(H1n, W2, b2, A2);
  head_tail<<<1, 256, 0, stream>>>(A2, g2, be2, W3, b3, (float*)d_out);
}

// Round 11
// 533.638 us; speedup vs baseline: 1.1644x; 1.1644x over previous
//
#include <hip/hip_runtime.h>
#include <math.h>

#define HH 128   // hidden dim (both layers) == input F
#define PS 16    // pool slices per graph

typedef unsigned short bhalf;

__device__ __forceinline__ float dot4(float4 a, float4 b){
  return a.x*b.x + a.y*b.y + a.z*b.z + a.w*b.w;
}

// fast sigmoid: v_rcp_f32 instead of full IEEE divide
__device__ __forceinline__ float sigf(float t){
  return __builtin_amdgcn_rcpf(1.f + __expf(-t));
}

// f32 <-> bf16 (round-to-nearest-even)
__device__ __forceinline__ bhalf f2b(float f){
  union{ float f; unsigned u; } x; x.f = f;
  unsigned r = x.u + 0x7FFFu + ((x.u >> 16) & 1u);
  return (bhalf)(r >> 16);
}
__device__ __forceinline__ float b2f(bhalf h){
  union{ unsigned u; float f; } x; x.u = ((unsigned)h) << 16;
  return x.f;
}

// ---------------------------------------------------------------------------
// GEMM v5 layout (round-7, measured 0 bank conflicts, ~111 us): BM=64, BK=64,
// stride-68 LDS rows. m = blockIdx.x & 3 selects {K,Q,V,skip}.
// NEW this round: Q (m=1) and V (m=2) outputs are stored as bf16 -> halves
// the gather traffic in node_agg. K and skip stay f32.
// ---------------------------------------------------------------------------
template<bool RELU>
__global__ __launch_bounds__(256) void gemm_tile(
    const float* __restrict__ X,
    const float* __restrict__ Wk, const float* __restrict__ bk,
    const float* __restrict__ Wq, const float* __restrict__ bq,
    const float* __restrict__ Wv, const float* __restrict__ bv,
    const float* __restrict__ Ws, const float* __restrict__ bs,
    float* __restrict__ Ko, bhalf* __restrict__ Qb,
    bhalf* __restrict__ Vb, float* __restrict__ So, int n)
{
  __shared__ float sX[64 * 68];    // 17.4 KB
  __shared__ float sW[128 * 68];   // 34.8 KB

  const int m = blockIdx.x & 3;
  const float* W; const float* B;
  if (m == 0){ W = Wk; B = bk; }
  else if (m == 1){ W = Wq; B = bq; }
  else if (m == 2){ W = Wv; B = bv; }
  else { W = Ws; B = bs; }

  const int tid = threadIdx.x;
  const int tx = tid & 15;       // col group: cols tx + 16j, j=0..7
  const int ty = tid >> 4;       // row group: rows ty + 16i, i=0..3
  const int row0 = (blockIdx.x >> 2) * 64;

  float acc[4][8];
#pragma unroll
  for (int i = 0; i < 4; ++i)
#pragma unroll
    for (int j = 0; j < 8; ++j) acc[i][j] = 0.f;

  for (int kc = 0; kc < 2; ++kc){
    const int k0q = kc * 16;  // float4 offset of this k-chunk
    // stage X chunk: 64 rows x 16 float4
    for (int fi = tid; fi < 64 * 16; fi += 256){
      int r = fi >> 4, kq = fi & 15;
      int gr = row0 + r;
      float4 v = make_float4(0.f, 0.f, 0.f, 0.f);
      if (gr < n){
        v = ((const float4*)X)[(size_t)gr * 32 + k0q + kq];
        if (RELU){
          v.x = fmaxf(v.x, 0.f); v.y = fmaxf(v.y, 0.f);
          v.z = fmaxf(v.z, 0.f); v.w = fmaxf(v.w, 0.f);
        }
      }
      *(float4*)&sX[r * 68 + kq * 4] = v;
    }
    // stage W chunk: 128 cols x 16 float4
    for (int fi = tid; fi < 128 * 16; fi += 256){
      int c = fi >> 4, kq = fi & 15;
      float4 v = ((const float4*)W)[c * 32 + k0q + kq];
      *(float4*)&sW[c * 68 + kq * 4] = v;
    }
    __syncthreads();

    for (int k = 0; k < 64; k += 4){
      float4 a[4], w[8];
#pragma unroll
      for (int i = 0; i < 4; ++i)
        a[i] = *(const float4*)&sX[(ty + 16 * i) * 68 + k];
#pragma unroll
      for (int j = 0; j < 8; ++j)
        w[j] = *(const float4*)&sW[(tx + 16 * j) * 68 + k];
#pragma unroll
      for (int i = 0; i < 4; ++i)
#pragma unroll
        for (int j = 0; j < 8; ++j){
          float s = acc[i][j];
          s = fmaf(a[i].x, w[j].x, s);
          s = fmaf(a[i].y, w[j].y, s);
          s = fmaf(a[i].z, w[j].z, s);
          s = fmaf(a[i].w, w[j].w, s);
          acc[i][j] = s;
        }
    }
    __syncthreads();
  }

  if (m == 0 || m == 3){
    float* D = (m == 0) ? Ko : So;
#pragma unroll
    for (int i = 0; i < 4; ++i){
      int gr = row0 + ty + 16 * i;
      if (gr < n){
#pragma unroll
        for (int j = 0; j < 8; ++j){
          int c = tx + 16 * j;
          D[(size_t)gr * HH + c] = acc[i][j] + B[c];
        }
      }
    }
  } else {
    bhalf* Db = (m == 1) ? Qb : Vb;
#pragma unroll
    for (int i = 0; i < 4; ++i){
      int gr = row0 + ty + 16 * i;
      if (gr < n){
#pragma unroll
        for (int j = 0; j < 8; ++j){
          int c = tx + 16 * j;
          Db[(size_t)gr * HH + c] = f2b(acc[i][j] + B[c]);
        }
      }
    }
  }
}

// ---------------------------------------------------------------------------
// CSR build
// ---------------------------------------------------------------------------
__global__ void zero_int(int* __restrict__ p, int n){
  int i = blockIdx.x * blockDim.x + threadIdx.x;
  if (i < n) p[i] = 0;
}

__global__ void hist_dst(const int* __restrict__ ei, int E, int* __restrict__ cnt){
  int e = blockIdx.x * blockDim.x + threadIdx.x;
  if (e < E) atomicAdd(&cnt[ei[E + e]], 1);
}

__global__ __launch_bounds__(256) void scan1(const int* __restrict__ cnt, int n,
                                             int* __restrict__ excl, int* __restrict__ bsum){
  __shared__ int s[256];
  int t = threadIdx.x;
  int i = blockIdx.x * 256 + t;
  int v = (i < n) ? cnt[i] : 0;
  s[t] = v;
  __syncthreads();
  for (int off = 1; off < 256; off <<= 1){
    int u = (t >= off) ? s[t - off] : 0;
    __syncthreads();
    s[t] += u;
    __syncthreads();
  }
  if (i < n) excl[i] = s[t] - v;
  if (t == 255) bsum[blockIdx.x] = s[255];
}

__global__ __launch_bounds__(256) void scan2(int* __restrict__ bsum, int nb){
  __shared__ int s[256];
  int t = threadIdx.x;
  int v = (t < nb) ? bsum[t] : 0;
  s[t] = v;
  __syncthreads();
  for (int off = 1; off < 256; off <<= 1){
    int u = (t >= off) ? s[t - off] : 0;
    __syncthreads();
    s[t] += u;
    __syncthreads();
  }
  if (t < nb) bsum[t] = s[t] - v;
}

__global__ void scan3(int* __restrict__ row_start, const int* __restrict__ bsum,
                      int n, int E, int* __restrict__ cursor){
  int i = blockIdx.x * blockDim.x + threadIdx.x;
  if (i < n){
    int v = row_start[i] + bsum[i >> 8];
    row_start[i] = v;
    cursor[i] = v;
  }
  if (i == n) row_start[n] = E;
}

__global__ void scatter_src(const int* __restrict__ ei, int E,
                            int* __restrict__ cursor, int* __restrict__ csr_src){
  int e = blockIdx.x * blockDim.x + threadIdx.x;
  if (e < E){
    int d = ei[E + e];
    int pos = atomicAdd(&cursor[d], 1);
    csr_src[pos] = ei[e];
  }
}

// ---------------------------------------------------------------------------
// Node-centric aggregate: one wave per dst node, 2 feats per lane.
// Q/V gathers are bf16 (ushort2 per lane = 256B per row) -> half traffic.
// ---------------------------------------------------------------------------
__global__ __launch_bounds__(256) void node_agg(
    const float* __restrict__ Kx, const bhalf* __restrict__ Qb,
    const bhalf* __restrict__ Vb, const float* __restrict__ Sx,
    const int* __restrict__ row_start, const int* __restrict__ csr_src,
    int n, float* __restrict__ H)
{
  int w = blockIdx.x * 4 + (threadIdx.x >> 6);
  w = __builtin_amdgcn_readfirstlane(w);
  if (w >= n) return;
  int lane = threadIdx.x & 63;

  float2 kd = ((const float2*)(Kx + (size_t)w * HH))[lane];
  float ax = 0.f, ay = 0.f;
  int j = row_start[w];
  const int jend = row_start[w + 1];

  for (; j + 3 < jend; j += 4){
    int s0 = csr_src[j],     s1 = csr_src[j + 1];
    int s2 = csr_src[j + 2], s3 = csr_src[j + 3];
    ushort2 q0 = ((const ushort2*)(Qb + (size_t)s0 * HH))[lane];
    ushort2 v0 = ((const ushort2*)(Vb + (size_t)s0 * HH))[lane];
    ushort2 q1 = ((const ushort2*)(Qb + (size_t)s1 * HH))[lane];
    ushort2 v1 = ((const ushort2*)(Vb + (size_t)s1 * HH))[lane];
    ushort2 q2 = ((const ushort2*)(Qb + (size_t)s2 * HH))[lane];
    ushort2 v2 = ((const ushort2*)(Vb + (size_t)s2 * HH))[lane];
    ushort2 q3 = ((const ushort2*)(Qb + (size_t)s3 * HH))[lane];
    ushort2 v3 = ((const ushort2*)(Vb + (size_t)s3 * HH))[lane];
    ax = fmaf(sigf(kd.x + b2f(q0.x)), b2f(v0.x), ax);
    ay = fmaf(sigf(kd.y + b2f(q0.y)), b2f(v0.y), ay);
    ax = fmaf(sigf(kd.x + b2f(q1.x)), b2f(v1.x), ax);
    ay = fmaf(sigf(kd.y + b2f(q1.y)), b2f(v1.y), ay);
    ax = fmaf(sigf(kd.x + b2f(q2.x)), b2f(v2.x), ax);
    ay = fmaf(sigf(kd.y + b2f(q2.y)), b2f(v2.y), ay);
    ax = fmaf(sigf(kd.x + b2f(q3.x)), b2f(v3.x), ax);
    ay = fmaf(sigf(kd.y + b2f(q3.y)), b2f(v3.y), ay);
  }
  for (; j < jend; ++j){
    int sA = csr_src[j];
    ushort2 qa = ((const ushort2*)(Qb + (size_t)sA * HH))[lane];
    ushort2 va = ((const ushort2*)(Vb + (size_t)sA * HH))[lane];
    ax = fmaf(sigf(kd.x + b2f(qa.x)), b2f(va.x), ax);
    ay = fmaf(sigf(kd.y + b2f(qa.y)), b2f(va.y), ay);
  }
  float2 sk = ((const float2*)(Sx + (size_t)w * HH))[lane];
  float2 o; o.x = ax + sk.x; o.y = ay + sk.y;
  ((float2*)(H + (size_t)w * HH))[lane] = o;
}

// ---------------------------------------------------------------------------
// Pool, two-phase.
// ---------------------------------------------------------------------------
__global__ __launch_bounds__(256) void pool_partial(
    const float* __restrict__ Hn, const int* __restrict__ batch,
    int n, float* __restrict__ pmax, float* __restrict__ psum)
{
  int g = blockIdx.x;
  int s = blockIdx.y;
  int lo = 0, hi = n;
  while (lo < hi){ int mid = (lo + hi) >> 1; if (batch[mid] < g) lo = mid + 1; else hi = mid; }
  int s0 = lo;
  lo = s0; hi = n;
  while (lo < hi){ int mid = (lo + hi) >> 1; if (batch[mid] < g + 1) lo = mid + 1; else hi = mid; }
  int e0 = lo;

  int len = e0 - s0;
  int a0 = s0 + (int)(((long long)len * s) / PS);
  int a1 = s0 + (int)(((long long)len * (s + 1)) / PS);

  int t = threadIdx.x;
  int f = t & 127;
  int half = t >> 7;
  float mx = -INFINITY;
  float sm = 0.f;
  for (int i = a0 + half; i < a1; i += 2){
    float v = Hn[(size_t)i * HH + f];
    mx = fmaxf(mx, v);
    sm += v;
  }
  __shared__ float smx[256], ssm[256];
  smx[t] = mx; ssm[t] = sm;
  __syncthreads();
  if (half == 0){
    mx = fmaxf(mx, smx[t + 128]);
    sm += ssm[t + 128];
    size_t o = ((size_t)g * PS + s) * 128 + f;
    pmax[o] = mx;
    psum[o] = sm;
  }
}

__global__ __launch_bounds__(128) void pool_reduce(
    const float* __restrict__ pmax, const float* __restrict__ psum,
    const int* __restrict__ batch, int n, float* __restrict__ Fp)
{
  int g = blockIdx.x;
  int f = threadIdx.x;
  int lo = 0, hi = n;
  while (lo < hi){ int mid = (lo + hi) >> 1; if (batch[mid] < g) lo = mid + 1; else hi = mid; }
  int s0 = lo;
  lo = s0; hi = n;
  while (lo < hi){ int mid = (lo + hi) >> 1; if (batch[mid] < g + 1) lo = mid + 1; else hi = mid; }
  int cnt = lo - s0;

  float mx = -INFINITY, sm = 0.f;
#pragma unroll
  for (int s = 0; s < PS; ++s){
    size_t o = ((size_t)g * PS + s) * 128 + f;
    mx = fmaxf(mx, pmax[o]);
    sm += psum[o];
  }
  float mean = sm / fmaxf((float)cnt, 1.0f);
  Fp[(size_t)g * 256 + f]       = mx;
  Fp[(size_t)g * 256 + 128 + f] = mean;
}

// ---------------------------------------------------------------------------
// MLP head (parallel)
// ---------------------------------------------------------------------------
__global__ __launch_bounds__(256) void head_gemm1(
    const float* __restrict__ Fp, const float* __restrict__ W1,
    const float* __restrict__ b1, float* __restrict__ A1)
{
  int idx = blockIdx.x * 256 + threadIdx.x;
  int r = idx >> 7, c = idx & 127;
  const float4* f4 = (const float4*)(Fp + r * 256);
  const float4* w4 = (const float4*)(W1 + c * 256);
  float acc = b1[c];
#pragma unroll
  for (int k = 0; k < 64; ++k) acc += dot4(f4[k], w4[k]);
  A1[idx] = acc;
}

__global__ __launch_bounds__(256) void head_bn_relu1(
    const float* __restrict__ A1, const float* __restrict__ g1,
    const float* __restrict__ be1, float* __restrict__ H1n)
{
  __shared__ float sMS[256];
  int t = threadIdx.x;
  if (t < 128){
    float m = 0.f, m2 = 0.f;
    for (int r = 0; r < 64; ++r){ float v = A1[r * 128 + t]; m += v; m2 += v * v; }
    m *= (1.f / 64.f); m2 *= (1.f / 64.f);
    float var = m2 - m * m;
    sMS[t] = m;
    sMS[128 + t] = g1[t] * rsqrtf(var + 1e-5f);
  }
  __syncthreads();
  for (int i = t; i < 64 * 128; i += 256){
    int c = i & 127;
    float v = (A1[i] - sMS[c]) * sMS[128 + c] + be1[c];
    H1n[i] = fmaxf(v, 0.f);
  }
}

__global__ __launch_bounds__(256) void head_gemm2(
    const float* __restrict__ H1n, const float* __restrict__ W2,
    const float* __restrict__ b2, float* __restrict__ A2)
{
  int idx = blockIdx.x * 256 + threadIdx.x;
  int r = idx >> 6, c = idx & 63;
  const float4* f4 = (const float4*)(H1n + r * 128);
  const float4* w4 = (const float4*)(W2 + c * 128);
  float acc = b2[c];
#pragma unroll
  for (int k = 0; k < 32; ++k) acc += dot4(f4[k], w4[k]);
  A2[idx] = acc;
}

__global__ __launch_bounds__(256) void head_tail(
    const float* __restrict__ A2, const float* __restrict__ g2,
    const float* __restrict__ be2, const float* __restrict__ W3,
    const float* __restrict__ b3, float* __restrict__ out)
{
  __shared__ float sH[64 * 64];
  __shared__ float sMS[128];
  int t = threadIdx.x;
  for (int i = t; i < 64 * 64 / 4; i += 256)
    ((float4*)sH)[i] = ((const float4*)A2)[i];
  __syncthreads();
  if (t < 64){
    float m = 0.f, m2 = 0.f;
    for (int r = 0; r < 64; ++r){ float v = sH[r * 64 + t]; m += v; m2 += v * v; }
    m *= (1.f / 64.f); m2 *= (1.f / 64.f);
    float var = m2 - m * m;
    sMS[t] = m;
    sMS[64 + t] = g2[t] * rsqrtf(var + 1e-5f);
  }
  __syncthreads();
  for (int i = t; i < 64 * 64; i += 256){
    int c = i & 63;
    float v = (sH[i] - sMS[c]) * sMS[64 + c] + be2[c];
    sH[i] = fmaxf(v, 0.f);
  }
  __syncthreads();
  if (t < 64){
    float acc = b3[0];
#pragma unroll
    for (int k = 0; k < 64; ++k) acc += sH[t * 64 + k] * W3[k];
    out[t] = acc;
  }
}

// ---------------------------------------------------------------------------
extern "C" void kernel_launch(void* const* d_in, const int* in_sizes, int n_in,
                              void* d_out, int out_size, void* d_ws, size_t ws_size,
                              hipStream_t stream)
{
  const float* x     = (const float*)d_in[0];
  const int*   ei    = (const int*)d_in[1];
  const int*   batch = (const int*)d_in[2];

  const float* l0Wk = (const float*)d_in[3];  const float* l0bk = (const float*)d_in[4];
  const float* l0Wq = (const float*)d_in[5];  const float* l0bq = (const float*)d_in[6];
  const float* l0Wv = (const float*)d_in[7];  const float* l0bv = (const float*)d_in[8];
  const float* l0Ws = (const float*)d_in[9];  const float* l0bs = (const float*)d_in[10];
  const float* l1Wk = (const float*)d_in[11]; const float* l1bk = (const float*)d_in[12];
  const float* l1Wq = (const float*)d_in[13]; const float* l1bq = (const float*)d_in[14];
  const float* l1Wv = (const float*)d_in[15]; const float* l1bv = (const float*)d_in[16];
  const float* l1Ws = (const float*)d_in[17]; const float* l1bs = (const float*)d_in[18];

  const float* W1  = (const float*)d_in[19]; const float* b1  = (const float*)d_in[20];
  const float* g1  = (const float*)d_in[21]; const float* be1 = (const float*)d_in[22];
  const float* W2  = (const float*)d_in[23]; const float* b2  = (const float*)d_in[24];
  const float* g2  = (const float*)d_in[25]; const float* be2 = (const float*)d_in[26];
  const float* W3  = (const float*)d_in[27]; const float* b3  = (const float*)d_in[28];

  const int N = in_sizes[0] / HH;
  const int E = in_sizes[1] / 2;
  const int G = out_size;
  const size_t NH = (size_t)N * HH;

  float* ws = (float*)d_ws;
  float* K  = ws;                               // NH f32
  float* H0 = K + NH;                           // NH f32
  float* H1 = H0 + NH;                          // NH f32
  float* Fp = H1 + NH;                          // G*256
  float* A1  = Fp + (size_t)G * 256;            // 64*128
  float* H1n = A1 + 64 * 128;
  float* A2  = H1n + 64 * 128;                  // 64*64
  float* pmax = A2 + 64 * 64;                   // G*PS*128
  float* psum = pmax + (size_t)G * PS * 128;    // G*PS*128
  bhalf* Qb = (bhalf*)(psum + (size_t)G * PS * 128);  // NH bf16
  bhalf* Vb = Qb + NH;                                // NH bf16
  int* ip        = (int*)(Vb + NH);
  int* row_start = ip;                 // N+1
  int* cursor    = row_start + (N + 1);
  int* cnt       = cursor + N;
  int* csr_src   = cnt + N;            // E
  int* bsum      = csr_src + E;        // 256

  const int nb   = (N + 255) / 256;
  const int ebl  = (E + 255) / 256;
  const int gemm_blocks = ((N + 63) / 64) * 4;   // 4 matrices interleaved
  const int agg_blocks = (N + 3) / 4;

  // --- CSR build ---
  zero_int<<<nb, 256, 0, stream>>>(cnt, N);
  hist_dst<<<ebl, 256, 0, stream>>>(ei, E, cnt);
  scan1<<<nb, 256, 0, stream>>>(cnt, N, row_start, bsum);
  scan2<<<1, 256, 0, stream>>>(bsum, nb);
  scan3<<<(N + 256) / 256, 256, 0, stream>>>(row_start, bsum, N, E, cursor);
  scatter_src<<<ebl, 256, 0, stream>>>(ei, E, cursor, csr_src);

  // --- Layer 0 ---
  gemm_tile<false><<<gemm_blocks, 256, 0, stream>>>(
      x, l0Wk, l0bk, l0Wq, l0bq, l0Wv, l0bv, l0Ws, l0bs, K, Qb, Vb, H0, N);
  node_agg<<<agg_blocks, 256, 0, stream>>>(K, Qb, Vb, H0, row_start, csr_src, N, H0);

  // --- Layer 1 ---
  gemm_tile<true><<<gemm_blocks, 256, 0, stream>>>(
      H0, l1Wk, l1bk, l1Wq, l1bq, l1Wv, l1bv, l1Ws, l1bs, K, Qb, Vb, H1, N);
  node_agg<<<agg_blocks, 256, 0, stream>>>(K, Qb, Vb, H1, row_start, csr_src, N, H1);

  // --- Pool (two-phase) + head ---
  pool_partial<<<dim3(G, PS), 256, 0, stream>>>(H1, batch, N, pmax, psum);
  pool_reduce<<<G, 128, 0, stream>>>(pmax, psum, batch, N, Fp);
  head_gemm1<<<32, 256, 0, stream>>>(Fp, W1, b1, A1);
  head_bn_relu1<<<1, 256, 0, stream>>>(A1, g1, be1, H1n);
  head_gemm2<<<16, 256, 0, stream>>>(H1n, W2, b2, A2);
  head_tail<<<1, 256, 0, stream>>>(A2, g2, be2, W3, b3, (float*)d_out);
}

// Round 12
// 507.501 us; speedup vs baseline: 1.2244x; 1.0515x over previous
//
#include <hip/hip_runtime.h>
#include <math.h>

#define HH 128   // hidden dim (both layers) == input F
#define PS 16    // pool slices per graph

typedef unsigned short bhalf;
typedef __attribute__((ext_vector_type(8))) short bf16x8;   // 8 bf16 = 4 VGPRs
typedef __attribute__((ext_vector_type(4))) float f32x4;

__device__ __forceinline__ float dot4(float4 a, float4 b){
  return a.x*b.x + a.y*b.y + a.z*b.z + a.w*b.w;
}

// fast sigmoid: v_rcp_f32 instead of full IEEE divide
__device__ __forceinline__ float sigf(float t){
  return __builtin_amdgcn_rcpf(1.f + __expf(-t));
}

// f32 <-> bf16 (round-to-nearest-even)
__device__ __forceinline__ bhalf f2b(float f){
  union{ float f; unsigned u; } x; x.f = f;
  unsigned r = x.u + 0x7FFFu + ((x.u >> 16) & 1u);
  return (bhalf)(r >> 16);
}
__device__ __forceinline__ float b2f(bhalf h){
  union{ unsigned u; float f; } x; x.u = ((unsigned)h) << 16;
  return x.f;
}

// ---------------------------------------------------------------------------
// f32 -> bf16 conversion (optionally fused ReLU), float4-vectorized.
// ---------------------------------------------------------------------------
template<bool RELU>
__global__ __launch_bounds__(256) void conv_x(
    const float* __restrict__ X, bhalf* __restrict__ Xb, int n4)
{
  int i = blockIdx.x * 256 + threadIdx.x;
  if (i < n4){
    float4 v = ((const float4*)X)[i];
    if (RELU){
      v.x = fmaxf(v.x, 0.f); v.y = fmaxf(v.y, 0.f);
      v.z = fmaxf(v.z, 0.f); v.w = fmaxf(v.w, 0.f);
    }
    ushort4 o;
    o.x = f2b(v.x); o.y = f2b(v.y); o.z = f2b(v.z); o.w = f2b(v.w);
    ((ushort4*)Xb)[i] = o;
  }
}

// Convert 4 weight matrices (128x128 f32 each) into contiguous bf16 [4][16384].
__global__ __launch_bounds__(256) void conv_w4(
    const float* __restrict__ w0, const float* __restrict__ w1,
    const float* __restrict__ w2, const float* __restrict__ w3,
    bhalf* __restrict__ dst)
{
  int i = blockIdx.x * 256 + threadIdx.x;   // < 4*16384
  int sel = i >> 14, off = i & 16383;
  const float* s = (sel == 0) ? w0 : (sel == 1) ? w1 : (sel == 2) ? w2 : w3;
  dst[i] = f2b(s[off]);
}

// ---------------------------------------------------------------------------
// MFMA GEMM: out = X @ W.T + b for {K,Q,V,skip} (m = blockIdx.x & 3).
// 4 waves/block; wave w owns rows row0+w*16 .. +15, all 128 cols.
// mfma_f32_16x16x32_bf16: A-frag lane(l): row = l&15, k = (l>>4)*8+j
// (contiguous bf16x8); B-frag: col = l&15, k same -> W[col][k] contiguous
// since W is [out][in] (= B^T). C/D: col = l&15, row = (l>>4)*4 + reg.
// No LDS, no barriers; X rows read exactly once; W (32KB bf16) L1/L2-hot.
// ---------------------------------------------------------------------------
__global__ __launch_bounds__(256) void gemm_mfma(
    const bhalf* __restrict__ Xb, const bhalf* __restrict__ Wb4,
    const float* __restrict__ bk, const float* __restrict__ bq,
    const float* __restrict__ bv, const float* __restrict__ bs,
    float* __restrict__ Ko, bhalf* __restrict__ Qb,
    bhalf* __restrict__ Vb, float* __restrict__ So, int n)
{
  const int m = blockIdx.x & 3;
  const bhalf* W = Wb4 + m * (HH * HH);
  const float* B = (m == 0) ? bk : (m == 1) ? bq : (m == 2) ? bv : bs;

  const int wv   = threadIdx.x >> 6;
  const int lane = threadIdx.x & 63;
  const int row0 = (blockIdx.x >> 2) * 64 + wv * 16;
  const int la = lane & 15;       // A-row / B-col within tile
  const int lb = lane >> 4;       // k-octet selector

  f32x4 acc[8];
#pragma unroll
  for (int ct = 0; ct < 8; ++ct) acc[ct] = (f32x4){0.f, 0.f, 0.f, 0.f};

  const bhalf* ap = Xb + (size_t)(row0 + la) * HH + lb * 8;
  const bhalf* bp = W + (size_t)la * HH + lb * 8;

#pragma unroll
  for (int ks = 0; ks < 4; ++ks){
    bf16x8 a = *(const bf16x8*)(ap + ks * 32);
#pragma unroll
    for (int ct = 0; ct < 8; ++ct){
      bf16x8 b = *(const bf16x8*)(bp + (size_t)ct * 16 * HH + ks * 32);
      acc[ct] = __builtin_amdgcn_mfma_f32_16x16x32_bf16(a, b, acc[ct], 0, 0, 0);
    }
  }

  const int r0 = lb * 4;
  if (m == 0 || m == 3){
    float* D = (m == 0) ? Ko : So;
#pragma unroll
    for (int ct = 0; ct < 8; ++ct){
      int col = ct * 16 + la;
      float bb = B[col];
#pragma unroll
      for (int r = 0; r < 4; ++r){
        int gr = row0 + r0 + r;
        if (gr < n) D[(size_t)gr * HH + col] = acc[ct][r] + bb;
      }
    }
  } else {
    bhalf* Db = (m == 1) ? Qb : Vb;
#pragma unroll
    for (int ct = 0; ct < 8; ++ct){
      int col = ct * 16 + la;
      float bb = B[col];
#pragma unroll
      for (int r = 0; r < 4; ++r){
        int gr = row0 + r0 + r;
        if (gr < n) Db[(size_t)gr * HH + col] = f2b(acc[ct][r] + bb);
      }
    }
  }
}

// ---------------------------------------------------------------------------
// CSR build
// ---------------------------------------------------------------------------
__global__ void zero_int(int* __restrict__ p, int n){
  int i = blockIdx.x * blockDim.x + threadIdx.x;
  if (i < n) p[i] = 0;
}

__global__ void hist_dst(const int* __restrict__ ei, int E, int* __restrict__ cnt){
  int e = blockIdx.x * blockDim.x + threadIdx.x;
  if (e < E) atomicAdd(&cnt[ei[E + e]], 1);
}

__global__ __launch_bounds__(256) void scan1(const int* __restrict__ cnt, int n,
                                             int* __restrict__ excl, int* __restrict__ bsum){
  __shared__ int s[256];
  int t = threadIdx.x;
  int i = blockIdx.x * 256 + t;
  int v = (i < n) ? cnt[i] : 0;
  s[t] = v;
  __syncthreads();
  for (int off = 1; off < 256; off <<= 1){
    int u = (t >= off) ? s[t - off] : 0;
    __syncthreads();
    s[t] += u;
    __syncthreads();
  }
  if (i < n) excl[i] = s[t] - v;
  if (t == 255) bsum[blockIdx.x] = s[255];
}

__global__ __launch_bounds__(256) void scan2(int* __restrict__ bsum, int nb){
  __shared__ int s[256];
  int t = threadIdx.x;
  int v = (t < nb) ? bsum[t] : 0;
  s[t] = v;
  __syncthreads();
  for (int off = 1; off < 256; off <<= 1){
    int u = (t >= off) ? s[t - off] : 0;
    __syncthreads();
    s[t] += u;
    __syncthreads();
  }
  if (t < nb) bsum[t] = s[t] - v;
}

__global__ void scan3(int* __restrict__ row_start, const int* __restrict__ bsum,
                      int n, int E, int* __restrict__ cursor){
  int i = blockIdx.x * blockDim.x + threadIdx.x;
  if (i < n){
    int v = row_start[i] + bsum[i >> 8];
    row_start[i] = v;
    cursor[i] = v;
  }
  if (i == n) row_start[n] = E;
}

__global__ void scatter_src(const int* __restrict__ ei, int E,
                            int* __restrict__ cursor, int* __restrict__ csr_src){
  int e = blockIdx.x * blockDim.x + threadIdx.x;
  if (e < E){
    int d = ei[E + e];
    int pos = atomicAdd(&cursor[d], 1);
    csr_src[pos] = ei[e];
  }
}

// ---------------------------------------------------------------------------
// Node-centric aggregate: one wave per dst node, 2 feats per lane.
// Q/V gathers bf16 (ushort2 per lane) -> half traffic. Unchanged from r11.
// ---------------------------------------------------------------------------
__global__ __launch_bounds__(256) void node_agg(
    const float* __restrict__ Kx, const bhalf* __restrict__ Qb,
    const bhalf* __restrict__ Vb, const float* __restrict__ Sx,
    const int* __restrict__ row_start, const int* __restrict__ csr_src,
    int n, float* __restrict__ H)
{
  int w = blockIdx.x * 4 + (threadIdx.x >> 6);
  w = __builtin_amdgcn_readfirstlane(w);
  if (w >= n) return;
  int lane = threadIdx.x & 63;

  float2 kd = ((const float2*)(Kx + (size_t)w * HH))[lane];
  float ax = 0.f, ay = 0.f;
  int j = row_start[w];
  const int jend = row_start[w + 1];

  for (; j + 3 < jend; j += 4){
    int s0 = csr_src[j],     s1 = csr_src[j + 1];
    int s2 = csr_src[j + 2], s3 = csr_src[j + 3];
    ushort2 q0 = ((const ushort2*)(Qb + (size_t)s0 * HH))[lane];
    ushort2 v0 = ((const ushort2*)(Vb + (size_t)s0 * HH))[lane];
    ushort2 q1 = ((const ushort2*)(Qb + (size_t)s1 * HH))[lane];
    ushort2 v1 = ((const ushort2*)(Vb + (size_t)s1 * HH))[lane];
    ushort2 q2 = ((const ushort2*)(Qb + (size_t)s2 * HH))[lane];
    ushort2 v2 = ((const ushort2*)(Vb + (size_t)s2 * HH))[lane];
    ushort2 q3 = ((const ushort2*)(Qb + (size_t)s3 * HH))[lane];
    ushort2 v3 = ((const ushort2*)(Vb + (size_t)s3 * HH))[lane];
    ax = fmaf(sigf(kd.x + b2f(q0.x)), b2f(v0.x), ax);
    ay = fmaf(sigf(kd.y + b2f(q0.y)), b2f(v0.y), ay);
    ax = fmaf(sigf(kd.x + b2f(q1.x)), b2f(v1.x), ax);
    ay = fmaf(sigf(kd.y + b2f(q1.y)), b2f(v1.y), ay);
    ax = fmaf(sigf(kd.x + b2f(q2.x)), b2f(v2.x), ax);
    ay = fmaf(sigf(kd.y + b2f(q2.y)), b2f(v2.y), ay);
    ax = fmaf(sigf(kd.x + b2f(q3.x)), b2f(v3.x), ax);
    ay = fmaf(sigf(kd.y + b2f(q3.y)), b2f(v3.y), ay);
  }
  for (; j < jend; ++j){
    int sA = csr_src[j];
    ushort2 qa = ((const ushort2*)(Qb + (size_t)sA * HH))[lane];
    ushort2 va = ((const ushort2*)(Vb + (size_t)sA * HH))[lane];
    ax = fmaf(sigf(kd.x + b2f(qa.x)), b2f(va.x), ax);
    ay = fmaf(sigf(kd.y + b2f(qa.y)), b2f(va.y), ay);
  }
  float2 sk = ((const float2*)(Sx + (size_t)w * HH))[lane];
  float2 o; o.x = ax + sk.x; o.y = ay + sk.y;
  ((float2*)(H + (size_t)w * HH))[lane] = o;
}

// ---------------------------------------------------------------------------
// Pool, two-phase.
// ---------------------------------------------------------------------------
__global__ __launch_bounds__(256) void pool_partial(
    const float* __restrict__ Hn, const int* __restrict__ batch,
    int n, float* __restrict__ pmax, float* __restrict__ psum)
{
  int g = blockIdx.x;
  int s = blockIdx.y;
  int lo = 0, hi = n;
  while (lo < hi){ int mid = (lo + hi) >> 1; if (batch[mid] < g) lo = mid + 1; else hi = mid; }
  int s0 = lo;
  lo = s0; hi = n;
  while (lo < hi){ int mid = (lo + hi) >> 1; if (batch[mid] < g + 1) lo = mid + 1; else hi = mid; }
  int e0 = lo;

  int len = e0 - s0;
  int a0 = s0 + (int)(((long long)len * s) / PS);
  int a1 = s0 + (int)(((long long)len * (s + 1)) / PS);

  int t = threadIdx.x;
  int f = t & 127;
  int half = t >> 7;
  float mx = -INFINITY;
  float sm = 0.f;
  for (int i = a0 + half; i < a1; i += 2){
    float v = Hn[(size_t)i * HH + f];
    mx = fmaxf(mx, v);
    sm += v;
  }
  __shared__ float smx[256], ssm[256];
  smx[t] = mx; ssm[t] = sm;
  __syncthreads();
  if (half == 0){
    mx = fmaxf(mx, smx[t + 128]);
    sm += ssm[t + 128];
    size_t o = ((size_t)g * PS + s) * 128 + f;
    pmax[o] = mx;
    psum[o] = sm;
  }
}

__global__ __launch_bounds__(128) void pool_reduce(
    const float* __restrict__ pmax, const float* __restrict__ psum,
    const int* __restrict__ batch, int n, float* __restrict__ Fp)
{
  int g = blockIdx.x;
  int f = threadIdx.x;
  int lo = 0, hi = n;
  while (lo < hi){ int mid = (lo + hi) >> 1; if (batch[mid] < g) lo = mid + 1; else hi = mid; }
  int s0 = lo;
  lo = s0; hi = n;
  while (lo < hi){ int mid = (lo + hi) >> 1; if (batch[mid] < g + 1) lo = mid + 1; else hi = mid; }
  int cnt = lo - s0;

  float mx = -INFINITY, sm = 0.f;
#pragma unroll
  for (int s = 0; s < PS; ++s){
    size_t o = ((size_t)g * PS + s) * 128 + f;
    mx = fmaxf(mx, pmax[o]);
    sm += psum[o];
  }
  float mean = sm / fmaxf((float)cnt, 1.0f);
  Fp[(size_t)g * 256 + f]       = mx;
  Fp[(size_t)g * 256 + 128 + f] = mean;
}

// ---------------------------------------------------------------------------
// MLP head (parallel)
// ---------------------------------------------------------------------------
__global__ __launch_bounds__(256) void head_gemm1(
    const float* __restrict__ Fp, const float* __restrict__ W1,
    const float* __restrict__ b1, float* __restrict__ A1)
{
  int idx = blockIdx.x * 256 + threadIdx.x;
  int r = idx >> 7, c = idx & 127;
  const float4* f4 = (const float4*)(Fp + r * 256);
  const float4* w4 = (const float4*)(W1 + c * 256);
  float acc = b1[c];
#pragma unroll
  for (int k = 0; k < 64; ++k) acc += dot4(f4[k], w4[k]);
  A1[idx] = acc;
}

__global__ __launch_bounds__(256) void head_bn_relu1(
    const float* __restrict__ A1, const float* __restrict__ g1,
    const float* __restrict__ be1, float* __restrict__ H1n)
{
  __shared__ float sMS[256];
  int t = threadIdx.x;
  if (t < 128){
    float m = 0.f, m2 = 0.f;
    for (int r = 0; r < 64; ++r){ float v = A1[r * 128 + t]; m += v; m2 += v * v; }
    m *= (1.f / 64.f); m2 *= (1.f / 64.f);
    float var = m2 - m * m;
    sMS[t] = m;
    sMS[128 + t] = g1[t] * rsqrtf(var + 1e-5f);
  }
  __syncthreads();
  for (int i = t; i < 64 * 128; i += 256){
    int c = i & 127;
    float v = (A1[i] - sMS[c]) * sMS[128 + c] + be1[c];
    H1n[i] = fmaxf(v, 0.f);
  }
}

__global__ __launch_bounds__(256) void head_gemm2(
    const float* __restrict__ H1n, const float* __restrict__ W2,
    const float* __restrict__ b2, float* __restrict__ A2)
{
  int idx = blockIdx.x * 256 + threadIdx.x;
  int r = idx >> 6, c = idx & 63;
  const float4* f4 = (const float4*)(H1n + r * 128);
  const float4* w4 = (const float4*)(W2 + c * 128);
  float acc = b2[c];
#pragma unroll
  for (int k = 0; k < 32; ++k) acc += dot4(f4[k], w4[k]);
  A2[idx] = acc;
}

__global__ __launch_bounds__(256) void head_tail(
    const float* __restrict__ A2, const float* __restrict__ g2,
    const float* __restrict__ be2, const float* __restrict__ W3,
    const float* __restrict__ b3, float* __restrict__ out)
{
  __shared__ float sH[64 * 64];
  __shared__ float sMS[128];
  int t = threadIdx.x;
  for (int i = t; i < 64 * 64 / 4; i += 256)
    ((float4*)sH)[i] = ((const float4*)A2)[i];
  __syncthreads();
  if (t < 64){
    float m = 0.f, m2 = 0.f;
    for (int r = 0; r < 64; ++r){ float v = sH[r * 64 + t]; m += v; m2 += v * v; }
    m *= (1.f / 64.f); m2 *= (1.f / 64.f);
    float var = m2 - m * m;
    sMS[t] = m;
    sMS[64 + t] = g2[t] * rsqrtf(var + 1e-5f);
  }
  __syncthreads();
  for (int i = t; i < 64 * 64; i += 256){
    int c = i & 63;
    float v = (sH[i] - sMS[c]) * sMS[64 + c] + be2[c];
    sH[i] = fmaxf(v, 0.f);
  }
  __syncthreads();
  if (t < 64){
    float acc = b3[0];
#pragma unroll
    for (int k = 0; k < 64; ++k) acc += sH[t * 64 + k] * W3[k];
    out[t] = acc;
  }
}

// ---------------------------------------------------------------------------
extern "C" void kernel_launch(void* const* d_in, const int* in_sizes, int n_in,
                              void* d_out, int out_size, void* d_ws, size_t ws_size,
                              hipStream_t stream)
{
  const float* x     = (const float*)d_in[0];
  const int*   ei    = (const int*)d_in[1];
  const int*   batch = (const int*)d_in[2];

  const float* l0Wk = (const float*)d_in[3];  const float* l0bk = (const float*)d_in[4];
  const float* l0Wq = (const float*)d_in[5];  const float* l0bq = (const float*)d_in[6];
  const float* l0Wv = (const float*)d_in[7];  const float* l0bv = (const float*)d_in[8];
  const float* l0Ws = (const float*)d_in[9];  const float* l0bs = (const float*)d_in[10];
  const float* l1Wk = (const float*)d_in[11]; const float* l1bk = (const float*)d_in[12];
  const float* l1Wq = (const float*)d_in[13]; const float* l1bq = (const float*)d_in[14];
  const float* l1Wv = (const float*)d_in[15]; const float* l1bv = (const float*)d_in[16];
  const float* l1Ws = (const float*)d_in[17]; const float* l1bs = (const float*)d_in[18];

  const float* W1  = (const float*)d_in[19]; const float* b1  = (const float*)d_in[20];
  const float* g1  = (const float*)d_in[21]; const float* be1 = (const float*)d_in[22];
  const float* W2  = (const float*)d_in[23]; const float* b2  = (const float*)d_in[24];
  const float* g2  = (const float*)d_in[25]; const float* be2 = (const float*)d_in[26];
  const float* W3  = (const float*)d_in[27]; const float* b3  = (const float*)d_in[28];

  const int N = in_sizes[0] / HH;
  const int E = in_sizes[1] / 2;
  const int G = out_size;
  const size_t NH = (size_t)N * HH;

  float* ws = (float*)d_ws;
  float* K  = ws;                               // NH f32
  float* H0 = K + NH;                           // NH f32
  float* H1 = H0 + NH;                          // NH f32
  float* Fp = H1 + NH;                          // G*256
  float* A1  = Fp + (size_t)G * 256;            // 64*128
  float* H1n = A1 + 64 * 128;
  float* A2  = H1n + 64 * 128;                  // 64*64
  float* pmax = A2 + 64 * 64;                   // G*PS*128
  float* psum = pmax + (size_t)G * PS * 128;    // G*PS*128
  bhalf* Qb  = (bhalf*)(psum + (size_t)G * PS * 128);  // NH bf16
  bhalf* Vb  = Qb + NH;                                // NH bf16
  bhalf* Xb  = Vb + NH;                                // NH bf16
  bhalf* Wb0 = Xb + NH;                                // 4*16384 bf16
  bhalf* Wb1 = Wb0 + 4 * HH * HH;                      // 4*16384 bf16
  int* ip        = (int*)(Wb1 + 4 * HH * HH);
  int* row_start = ip;                 // N+1
  int* cursor    = row_start + (N + 1);
  int* cnt       = cursor + N;
  int* csr_src   = cnt + N;            // E
  int* bsum      = csr_src + E;        // 256

  const int nb   = (N + 255) / 256;
  const int ebl  = (E + 255) / 256;
  const int conv_blocks = (int)((NH / 4 + 255) / 256);
  const int gemm_blocks = ((N + 63) / 64) * 4;   // 4 matrices interleaved
  const int agg_blocks = (N + 3) / 4;

  // --- CSR build ---
  zero_int<<<nb, 256, 0, stream>>>(cnt, N);
  hist_dst<<<ebl, 256, 0, stream>>>(ei, E, cnt);
  scan1<<<nb, 256, 0, stream>>>(cnt, N, row_start, bsum);
  scan2<<<1, 256, 0, stream>>>(bsum, nb);
  scan3<<<(N + 256) / 256, 256, 0, stream>>>(row_start, bsum, N, E, cursor);
  scatter_src<<<ebl, 256, 0, stream>>>(ei, E, cursor, csr_src);

  // --- weight conversions (tiny) ---
  conv_w4<<<(4 * HH * HH) / 256, 256, 0, stream>>>(l0Wk, l0Wq, l0Wv, l0Ws, Wb0);
  conv_w4<<<(4 * HH * HH) / 256, 256, 0, stream>>>(l1Wk, l1Wq, l1Wv, l1Ws, Wb1);

  // --- Layer 0 ---
  conv_x<false><<<conv_blocks, 256, 0, stream>>>(x, Xb, (int)(NH / 4));
  gemm_mfma<<<gemm_blocks, 256, 0, stream>>>(
      Xb, Wb0, l0bk, l0bq, l0bv, l0bs, K, Qb, Vb, H0, N);
  node_agg<<<agg_blocks, 256, 0, stream>>>(K, Qb, Vb, H0, row_start, csr_src, N, H0);

  // --- Layer 1 (ReLU folded into conversion) ---
  conv_x<true><<<conv_blocks, 256, 0, stream>>>(H0, Xb, (int)(NH / 4));
  gemm_mfma<<<gemm_blocks, 256, 0, stream>>>(
      Xb, Wb1, l1bk, l1bq, l1bv, l1bs, K, Qb, Vb, H1, N);
  node_agg<<<agg_blocks, 256, 0, stream>>>(K, Qb, Vb, H1, row_start, csr_src, N, H1);

  // --- Pool (two-phase) + head ---
  pool_partial<<<dim3(G, PS), 256, 0, stream>>>(H1, batch, N, pmax, psum);
  pool_reduce<<<G, 128, 0, stream>>>(pmax, psum, batch, N, Fp);
  head_gemm1<<<32, 256, 0, stream>>>(Fp, W1, b1, A1);
  head_bn_relu1<<<1, 256, 0, stream>>>(A1, g1, be1, H1n);
  head_gemm2<<<16, 256, 0, stream>>>(H1n, W2, b2, A2);
  head_tail<<<1, 256, 0, stream>>>(A2, g2, be2, W3, b3, (float*)d_out);
}

// Round 13
// 505.254 us; speedup vs baseline: 1.2298x; 1.0044x over previous
//
#include <hip/hip_runtime.h>
#include <math.h>

#define HH 128   // hidden dim (both layers) == input F
#define PS 16    // pool slices per graph

typedef unsigned short bhalf;
typedef __attribute__((ext_vector_type(8))) short bf16x8;   // 8 bf16 = 4 VGPRs
typedef __attribute__((ext_vector_type(4))) float f32x4;

__device__ __forceinline__ float dot4(float4 a, float4 b){
  return a.x*b.x + a.y*b.y + a.z*b.z + a.w*b.w;
}

// fast sigmoid: v_rcp_f32 instead of full IEEE divide
__device__ __forceinline__ float sigf(float t){
  return __builtin_amdgcn_rcpf(1.f + __expf(-t));
}

// f32 <-> bf16 (round-to-nearest-even)
__device__ __forceinline__ bhalf f2b(float f){
  union{ float f; unsigned u; } x; x.f = f;
  unsigned r = x.u + 0x7FFFu + ((x.u >> 16) & 1u);
  return (bhalf)(r >> 16);
}
__device__ __forceinline__ float b2f(bhalf h){
  union{ unsigned u; float f; } x; x.u = ((unsigned)h) << 16;
  return x.f;
}

// ---------------------------------------------------------------------------
// f32 -> bf16 conversion (optionally fused ReLU), float4-vectorized.
// ---------------------------------------------------------------------------
template<bool RELU>
__global__ __launch_bounds__(256) void conv_x(
    const float* __restrict__ X, bhalf* __restrict__ Xb, int n4)
{
  int i = blockIdx.x * 256 + threadIdx.x;
  if (i < n4){
    float4 v = ((const float4*)X)[i];
    if (RELU){
      v.x = fmaxf(v.x, 0.f); v.y = fmaxf(v.y, 0.f);
      v.z = fmaxf(v.z, 0.f); v.w = fmaxf(v.w, 0.f);
    }
    ushort4 o;
    o.x = f2b(v.x); o.y = f2b(v.y); o.z = f2b(v.z); o.w = f2b(v.w);
    ((ushort4*)Xb)[i] = o;
  }
}

// Convert 4 weight matrices (128x128 f32 each) into contiguous bf16 [4][16384].
__global__ __launch_bounds__(256) void conv_w4(
    const float* __restrict__ w0, const float* __restrict__ w1,
    const float* __restrict__ w2, const float* __restrict__ w3,
    bhalf* __restrict__ dst)
{
  int i = blockIdx.x * 256 + threadIdx.x;   // < 4*16384
  int sel = i >> 14, off = i & 16383;
  const float* s = (sel == 0) ? w0 : (sel == 1) ? w1 : (sel == 2) ? w2 : w3;
  dst[i] = f2b(s[off]);
}

// ---------------------------------------------------------------------------
// MFMA GEMM, register-software-pipelined.
// 4 waves/block; wave w owns rows row0+w*16..+15, all 128 cols.
// All 4 A-frags loaded up front; B-frags double-buffered across the ks loop
// (issue loads of ks+1 before the MFMAs of ks) -> many loads in flight.
// Fragment mapping (m89/m92-verified): A lane l: row=l&15, k-octet=l>>4;
// B: col=l&15 (W is [out][in] = B^T, contiguous); C/D: col=l&15,
// row=(l>>4)*4+reg.
// ---------------------------------------------------------------------------
__global__ __launch_bounds__(256) void gemm_mfma(
    const bhalf* __restrict__ Xb, const bhalf* __restrict__ Wb4,
    const float* __restrict__ bk, const float* __restrict__ bq,
    const float* __restrict__ bv, const float* __restrict__ bs,
    float* __restrict__ Ko, bhalf* __restrict__ Qb,
    bhalf* __restrict__ Vb, float* __restrict__ So, int n)
{
  const int m = blockIdx.x & 3;
  const bhalf* W = Wb4 + m * (HH * HH);
  const float* B = (m == 0) ? bk : (m == 1) ? bq : (m == 2) ? bv : bs;

  const int wv   = threadIdx.x >> 6;
  const int lane = threadIdx.x & 63;
  const int row0 = (blockIdx.x >> 2) * 64 + wv * 16;
  const int la = lane & 15;       // A-row / B-col within tile
  const int lb = lane >> 4;       // k-octet selector

  const bhalf* ap = Xb + (size_t)(row0 + la) * HH + lb * 8;
  const bhalf* bp = W + (size_t)la * HH + lb * 8;

  // all 4 A-frags up front (16 VGPR)
  bf16x8 a[4];
#pragma unroll
  for (int ks = 0; ks < 4; ++ks) a[ks] = *(const bf16x8*)(ap + ks * 32);

  // B-frags for ks=0 (32 VGPR)
  bf16x8 bcur[8];
#pragma unroll
  for (int ct = 0; ct < 8; ++ct)
    bcur[ct] = *(const bf16x8*)(bp + (size_t)ct * 16 * HH);

  f32x4 acc[8];
#pragma unroll
  for (int ct = 0; ct < 8; ++ct) acc[ct] = (f32x4){0.f, 0.f, 0.f, 0.f};

#pragma unroll
  for (int ks = 0; ks < 4; ++ks){
    bf16x8 bnxt[8];
    if (ks < 3){
#pragma unroll
      for (int ct = 0; ct < 8; ++ct)
        bnxt[ct] = *(const bf16x8*)(bp + (size_t)ct * 16 * HH + (ks + 1) * 32);
    }
#pragma unroll
    for (int ct = 0; ct < 8; ++ct)
      acc[ct] = __builtin_amdgcn_mfma_f32_16x16x32_bf16(a[ks], bcur[ct], acc[ct], 0, 0, 0);
    if (ks < 3){
#pragma unroll
      for (int ct = 0; ct < 8; ++ct) bcur[ct] = bnxt[ct];
    }
  }

  const int r0 = lb * 4;
  if (m == 0 || m == 3){
    float* D = (m == 0) ? Ko : So;
#pragma unroll
    for (int ct = 0; ct < 8; ++ct){
      int col = ct * 16 + la;
      float bb = B[col];
#pragma unroll
      for (int r = 0; r < 4; ++r){
        int gr = row0 + r0 + r;
        if (gr < n) D[(size_t)gr * HH + col] = acc[ct][r] + bb;
      }
    }
  } else {
    bhalf* Db = (m == 1) ? Qb : Vb;
#pragma unroll
    for (int ct = 0; ct < 8; ++ct){
      int col = ct * 16 + la;
      float bb = B[col];
#pragma unroll
      for (int r = 0; r < 4; ++r){
        int gr = row0 + r0 + r;
        if (gr < n) Db[(size_t)gr * HH + col] = f2b(acc[ct][r] + bb);
      }
    }
  }
}

// ---------------------------------------------------------------------------
// CSR build
// ---------------------------------------------------------------------------
__global__ void zero_int(int* __restrict__ p, int n){
  int i = blockIdx.x * blockDim.x + threadIdx.x;
  if (i < n) p[i] = 0;
}

__global__ void hist_dst(const int* __restrict__ ei, int E, int* __restrict__ cnt){
  int e = blockIdx.x * blockDim.x + threadIdx.x;
  if (e < E) atomicAdd(&cnt[ei[E + e]], 1);
}

__global__ __launch_bounds__(256) void scan1(const int* __restrict__ cnt, int n,
                                             int* __restrict__ excl, int* __restrict__ bsum){
  __shared__ int s[256];
  int t = threadIdx.x;
  int i = blockIdx.x * 256 + t;
  int v = (i < n) ? cnt[i] : 0;
  s[t] = v;
  __syncthreads();
  for (int off = 1; off < 256; off <<= 1){
    int u = (t >= off) ? s[t - off] : 0;
    __syncthreads();
    s[t] += u;
    __syncthreads();
  }
  if (i < n) excl[i] = s[t] - v;
  if (t == 255) bsum[blockIdx.x] = s[255];
}

__global__ __launch_bounds__(256) void scan2(int* __restrict__ bsum, int nb){
  __shared__ int s[256];
  int t = threadIdx.x;
  int v = (t < nb) ? bsum[t] : 0;
  s[t] = v;
  __syncthreads();
  for (int off = 1; off < 256; off <<= 1){
    int u = (t >= off) ? s[t - off] : 0;
    __syncthreads();
    s[t] += u;
    __syncthreads();
  }
  if (t < nb) bsum[t] = s[t] - v;
}

__global__ void scan3(int* __restrict__ row_start, const int* __restrict__ bsum,
                      int n, int E, int* __restrict__ cursor){
  int i = blockIdx.x * blockDim.x + threadIdx.x;
  if (i < n){
    int v = row_start[i] + bsum[i >> 8];
    row_start[i] = v;
    cursor[i] = v;
  }
  if (i == n) row_start[n] = E;
}

__global__ void scatter_src(const int* __restrict__ ei, int E,
                            int* __restrict__ cursor, int* __restrict__ csr_src){
  int e = blockIdx.x * blockDim.x + threadIdx.x;
  if (e < E){
    int d = ei[E + e];
    int pos = atomicAdd(&cursor[d], 1);
    csr_src[pos] = ei[e];
  }
}

// ---------------------------------------------------------------------------
// Node-centric aggregate: one wave per dst node, 2 feats per lane.
// Q/V gathers bf16 (ushort2 per lane) -> half traffic.
// ---------------------------------------------------------------------------
__global__ __launch_bounds__(256) void node_agg(
    const float* __restrict__ Kx, const bhalf* __restrict__ Qb,
    const bhalf* __restrict__ Vb, const float* __restrict__ Sx,
    const int* __restrict__ row_start, const int* __restrict__ csr_src,
    int n, float* __restrict__ H)
{
  int w = blockIdx.x * 4 + (threadIdx.x >> 6);
  w = __builtin_amdgcn_readfirstlane(w);
  if (w >= n) return;
  int lane = threadIdx.x & 63;

  float2 kd = ((const float2*)(Kx + (size_t)w * HH))[lane];
  float ax = 0.f, ay = 0.f;
  int j = row_start[w];
  const int jend = row_start[w + 1];

  for (; j + 3 < jend; j += 4){
    int s0 = csr_src[j],     s1 = csr_src[j + 1];
    int s2 = csr_src[j + 2], s3 = csr_src[j + 3];
    ushort2 q0 = ((const ushort2*)(Qb + (size_t)s0 * HH))[lane];
    ushort2 v0 = ((const ushort2*)(Vb + (size_t)s0 * HH))[lane];
    ushort2 q1 = ((const ushort2*)(Qb + (size_t)s1 * HH))[lane];
    ushort2 v1 = ((const ushort2*)(Vb + (size_t)s1 * HH))[lane];
    ushort2 q2 = ((const ushort2*)(Qb + (size_t)s2 * HH))[lane];
    ushort2 v2 = ((const ushort2*)(Vb + (size_t)s2 * HH))[lane];
    ushort2 q3 = ((const ushort2*)(Qb + (size_t)s3 * HH))[lane];
    ushort2 v3 = ((const ushort2*)(Vb + (size_t)s3 * HH))[lane];
    ax = fmaf(sigf(kd.x + b2f(q0.x)), b2f(v0.x), ax);
    ay = fmaf(sigf(kd.y + b2f(q0.y)), b2f(v0.y), ay);
    ax = fmaf(sigf(kd.x + b2f(q1.x)), b2f(v1.x), ax);
    ay = fmaf(sigf(kd.y + b2f(q1.y)), b2f(v1.y), ay);
    ax = fmaf(sigf(kd.x + b2f(q2.x)), b2f(v2.x), ax);
    ay = fmaf(sigf(kd.y + b2f(q2.y)), b2f(v2.y), ay);
    ax = fmaf(sigf(kd.x + b2f(q3.x)), b2f(v3.x), ax);
    ay = fmaf(sigf(kd.y + b2f(q3.y)), b2f(v3.y), ay);
  }
  for (; j < jend; ++j){
    int sA = csr_src[j];
    ushort2 qa = ((const ushort2*)(Qb + (size_t)sA * HH))[lane];
    ushort2 va = ((const ushort2*)(Vb + (size_t)sA * HH))[lane];
    ax = fmaf(sigf(kd.x + b2f(qa.x)), b2f(va.x), ax);
    ay = fmaf(sigf(kd.y + b2f(qa.y)), b2f(va.y), ay);
  }
  float2 sk = ((const float2*)(Sx + (size_t)w * HH))[lane];
  float2 o; o.x = ax + sk.x; o.y = ay + sk.y;
  ((float2*)(H + (size_t)w * HH))[lane] = o;
}

// ---------------------------------------------------------------------------
// Pool, two-phase.
// ---------------------------------------------------------------------------
__global__ __launch_bounds__(256) void pool_partial(
    const float* __restrict__ Hn, const int* __restrict__ batch,
    int n, float* __restrict__ pmax, float* __restrict__ psum)
{
  int g = blockIdx.x;
  int s = blockIdx.y;
  int lo = 0, hi = n;
  while (lo < hi){ int mid = (lo + hi) >> 1; if (batch[mid] < g) lo = mid + 1; else hi = mid; }
  int s0 = lo;
  lo = s0; hi = n;
  while (lo < hi){ int mid = (lo + hi) >> 1; if (batch[mid] < g + 1) lo = mid + 1; else hi = mid; }
  int e0 = lo;

  int len = e0 - s0;
  int a0 = s0 + (int)(((long long)len * s) / PS);
  int a1 = s0 + (int)(((long long)len * (s + 1)) / PS);

  int t = threadIdx.x;
  int f = t & 127;
  int half = t >> 7;
  float mx = -INFINITY;
  float sm = 0.f;
  for (int i = a0 + half; i < a1; i += 2){
    float v = Hn[(size_t)i * HH + f];
    mx = fmaxf(mx, v);
    sm += v;
  }
  __shared__ float smx[256], ssm[256];
  smx[t] = mx; ssm[t] = sm;
  __syncthreads();
  if (half == 0){
    mx = fmaxf(mx, smx[t + 128]);
    sm += ssm[t + 128];
    size_t o = ((size_t)g * PS + s) * 128 + f;
    pmax[o] = mx;
    psum[o] = sm;
  }
}

__global__ __launch_bounds__(128) void pool_reduce(
    const float* __restrict__ pmax, const float* __restrict__ psum,
    const int* __restrict__ batch, int n, float* __restrict__ Fp)
{
  int g = blockIdx.x;
  int f = threadIdx.x;
  int lo = 0, hi = n;
  while (lo < hi){ int mid = (lo + hi) >> 1; if (batch[mid] < g) lo = mid + 1; else hi = mid; }
  int s0 = lo;
  lo = s0; hi = n;
  while (lo < hi){ int mid = (lo + hi) >> 1; if (batch[mid] < g + 1) lo = mid + 1; else hi = mid; }
  int cnt = lo - s0;

  float mx = -INFINITY, sm = 0.f;
#pragma unroll
  for (int s = 0; s < PS; ++s){
    size_t o = ((size_t)g * PS + s) * 128 + f;
    mx = fmaxf(mx, pmax[o]);
    sm += psum[o];
  }
  float mean = sm / fmaxf((float)cnt, 1.0f);
  Fp[(size_t)g * 256 + f]       = mx;
  Fp[(size_t)g * 256 + 128 + f] = mean;
}

// ---------------------------------------------------------------------------
// MLP head (parallel)
// ---------------------------------------------------------------------------
__global__ __launch_bounds__(256) void head_gemm1(
    const float* __restrict__ Fp, const float* __restrict__ W1,
    const float* __restrict__ b1, float* __restrict__ A1)
{
  int idx = blockIdx.x * 256 + threadIdx.x;
  int r = idx >> 7, c = idx & 127;
  const float4* f4 = (const float4*)(Fp + r * 256);
  const float4* w4 = (const float4*)(W1 + c * 256);
  float acc = b1[c];
#pragma unroll
  for (int k = 0; k < 64; ++k) acc += dot4(f4[k], w4[k]);
  A1[idx] = acc;
}

__global__ __launch_bounds__(256) void head_bn_relu1(
    const float* __restrict__ A1, const float* __restrict__ g1,
    const float* __restrict__ be1, float* __restrict__ H1n)
{
  __shared__ float sMS[256];
  int t = threadIdx.x;
  if (t < 128){
    float m = 0.f, m2 = 0.f;
    for (int r = 0; r < 64; ++r){ float v = A1[r * 128 + t]; m += v; m2 += v * v; }
    m *= (1.f / 64.f); m2 *= (1.f / 64.f);
    float var = m2 - m * m;
    sMS[t] = m;
    sMS[128 + t] = g1[t] * rsqrtf(var + 1e-5f);
  }
  __syncthreads();
  for (int i = t; i < 64 * 128; i += 256){
    int c = i & 127;
    float v = (A1[i] - sMS[c]) * sMS[128 + c] + be1[c];
    H1n[i] = fmaxf(v, 0.f);
  }
}

__global__ __launch_bounds__(256) void head_gemm2(
    const float* __restrict__ H1n, const float* __restrict__ W2,
    const float* __restrict__ b2, float* __restrict__ A2)
{
  int idx = blockIdx.x * 256 + threadIdx.x;
  int r = idx >> 6, c = idx & 63;
  const float4* f4 = (const float4*)(H1n + r * 128);
  const float4* w4 = (const float4*)(W2 + c * 128);
  float acc = b2[c];
#pragma unroll
  for (int k = 0; k < 32; ++k) acc += dot4(f4[k], w4[k]);
  A2[idx] = acc;
}

__global__ __launch_bounds__(256) void head_tail(
    const float* __restrict__ A2, const float* __restrict__ g2,
    const float* __restrict__ be2, const float* __restrict__ W3,
    const float* __restrict__ b3, float* __restrict__ out)
{
  __shared__ float sH[64 * 64];
  __shared__ float sMS[128];
  int t = threadIdx.x;
  for (int i = t; i < 64 * 64 / 4; i += 256)
    ((float4*)sH)[i] = ((const float4*)A2)[i];
  __syncthreads();
  if (t < 64){
    float m = 0.f, m2 = 0.f;
    for (int r = 0; r < 64; ++r){ float v = sH[r * 64 + t]; m += v; m2 += v * v; }
    m *= (1.f / 64.f); m2 *= (1.f / 64.f);
    float var = m2 - m * m;
    sMS[t] = m;
    sMS[64 + t] = g2[t] * rsqrtf(var + 1e-5f);
  }
  __syncthreads();
  for (int i = t; i < 64 * 64; i += 256){
    int c = i & 63;
    float v = (sH[i] - sMS[c]) * sMS[64 + c] + be2[c];
    sH[i] = fmaxf(v, 0.f);
  }
  __syncthreads();
  if (t < 64){
    float acc = b3[0];
#pragma unroll
    for (int k = 0; k < 64; ++k) acc += sH[t * 64 + k] * W3[k];
    out[t] = acc;
  }
}

// ---------------------------------------------------------------------------
extern "C" void kernel_launch(void* const* d_in, const int* in_sizes, int n_in,
                              void* d_out, int out_size, void* d_ws, size_t ws_size,
                              hipStream_t stream)
{
  const float* x     = (const float*)d_in[0];
  const int*   ei    = (const int*)d_in[1];
  const int*   batch = (const int*)d_in[2];

  const float* l0Wk = (const float*)d_in[3];  const float* l0bk = (const float*)d_in[4];
  const float* l0Wq = (const float*)d_in[5];  const float* l0bq = (const float*)d_in[6];
  const float* l0Wv = (const float*)d_in[7];  const float* l0bv = (const float*)d_in[8];
  const float* l0Ws = (const float*)d_in[9];  const float* l0bs = (const float*)d_in[10];
  const float* l1Wk = (const float*)d_in[11]; const float* l1bk = (const float*)d_in[12];
  const float* l1Wq = (const float*)d_in[13]; const float* l1bq = (const float*)d_in[14];
  const float* l1Wv = (const float*)d_in[15]; const float* l1bv = (const float*)d_in[16];
  const float* l1Ws = (const float*)d_in[17]; const float* l1bs = (const float*)d_in[18];

  const float* W1  = (const float*)d_in[19]; const float* b1  = (const float*)d_in[20];
  const float* g1  = (const float*)d_in[21]; const float* be1 = (const float*)d_in[22];
  const float* W2  = (const float*)d_in[23]; const float* b2  = (const float*)d_in[24];
  const float* g2  = (const float*)d_in[25]; const float* be2 = (const float*)d_in[26];
  const float* W3  = (const float*)d_in[27]; const float* b3  = (const float*)d_in[28];

  const int N = in_sizes[0] / HH;
  const int E = in_sizes[1] / 2;
  const int G = out_size;
  const size_t NH = (size_t)N * HH;

  float* ws = (float*)d_ws;
  float* K  = ws;                               // NH f32
  float* H0 = K + NH;                           // NH f32
  float* H1 = H0 + NH;                          // NH f32
  float* Fp = H1 + NH;                          // G*256
  float* A1  = Fp + (size_t)G * 256;            // 64*128
  float* H1n = A1 + 64 * 128;
  float* A2  = H1n + 64 * 128;                  // 64*64
  float* pmax = A2 + 64 * 64;                   // G*PS*128
  float* psum = pmax + (size_t)G * PS * 128;    // G*PS*128
  bhalf* Qb  = (bhalf*)(psum + (size_t)G * PS * 128);  // NH bf16
  bhalf* Vb  = Qb + NH;                                // NH bf16
  bhalf* Xb  = Vb + NH;                                // NH bf16
  bhalf* Wb0 = Xb + NH;                                // 4*16384 bf16
  bhalf* Wb1 = Wb0 + 4 * HH * HH;                      // 4*16384 bf16
  int* ip        = (int*)(Wb1 + 4 * HH * HH);
  int* row_start = ip;                 // N+1
  int* cursor    = row_start + (N + 1);
  int* cnt       = cursor + N;
  int* csr_src   = cnt + N;            // E
  int* bsum      = csr_src + E;        // 256

  const int nb   = (N + 255) / 256;
  const int ebl  = (E + 255) / 256;
  const int conv_blocks = (int)((NH / 4 + 255) / 256);
  const int gemm_blocks = ((N + 63) / 64) * 4;   // 4 matrices interleaved
  const int agg_blocks = (N + 3) / 4;

  // --- CSR build ---
  zero_int<<<nb, 256, 0, stream>>>(cnt, N);
  hist_dst<<<ebl, 256, 0, stream>>>(ei, E, cnt);
  scan1<<<nb, 256, 0, stream>>>(cnt, N, row_start, bsum);
  scan2<<<1, 256, 0, stream>>>(bsum, nb);
  scan3<<<(N + 256) / 256, 256, 0, stream>>>(row_start, bsum, N, E, cursor);
  scatter_src<<<ebl, 256, 0, stream>>>(ei, E, cursor, csr_src);

  // --- weight conversions (tiny) ---
  conv_w4<<<(4 * HH * HH) / 256, 256, 0, stream>>>(l0Wk, l0Wq, l0Wv, l0Ws, Wb0);
  conv_w4<<<(4 * HH * HH) / 256, 256, 0, stream>>>(l1Wk, l1Wq, l1Wv, l1Ws, Wb1);

  // --- Layer 0 ---
  conv_x<false><<<conv_blocks, 256, 0, stream>>>(x, Xb, (int)(NH / 4));
  gemm_mfma<<<gemm_blocks, 256, 0, stream>>>(
      Xb, Wb0, l0bk, l0bq, l0bv, l0bs, K, Qb, Vb, H0, N);
  node_agg<<<agg_blocks, 256, 0, stream>>>(K, Qb, Vb, H0, row_start, csr_src, N, H0);

  // --- Layer 1 (ReLU folded into conversion) ---
  conv_x<true><<<conv_blocks, 256, 0, stream>>>(H0, Xb, (int)(NH / 4));
  gemm_mfma<<<gemm_blocks, 256, 0, stream>>>(
      Xb, Wb1, l1bk, l1bq, l1bv, l1bs, K, Qb, Vb, H1, N);
  node_agg<<<agg_blocks, 256, 0, stream>>>(K, Qb, Vb, H1, row_start, csr_src, N, H1);

  // --- Pool (two-phase) + head ---
  pool_partial<<<dim3(G, PS), 256, 0, stream>>>(H1, batch, N, pmax, psum);
  pool_reduce<<<G, 128, 0, stream>>>(pmax, psum, batch, N, Fp);
  head_gemm1<<<32, 256, 0, stream>>>(Fp, W1, b1, A1);
  head_bn_relu1<<<1, 256, 0, stream>>>(A1, g1, be1, H1n);
  head_gemm2<<<16, 256, 0, stream>>>(H1n, W2, b2, A2);
  head_tail<<<1, 256, 0, stream>>>(A2, g2, be2, W3, b3, (float*)d_out);
}

// Round 14
// 418.818 us; speedup vs baseline: 1.4836x; 1.2064x over previous
//
#include <hip/hip_runtime.h>
#include <math.h>

#define HH 128   // hidden dim (both layers) == input F
#define PS 16    // pool slices per graph

typedef unsigned short bhalf;
typedef __attribute__((ext_vector_type(8))) short bf16x8;   // 8 bf16 = 4 VGPRs
typedef __attribute__((ext_vector_type(4))) float f32x4;

__device__ __forceinline__ float dot4(float4 a, float4 b){
  return a.x*b.x + a.y*b.y + a.z*b.z + a.w*b.w;
}

// fast sigmoid: v_rcp_f32 instead of full IEEE divide
__device__ __forceinline__ float sigf(float t){
  return __builtin_amdgcn_rcpf(1.f + __expf(-t));
}

// f32 <-> bf16 (round-to-nearest-even)
__device__ __forceinline__ bhalf f2b(float f){
  union{ float f; unsigned u; } x; x.f = f;
  unsigned r = x.u + 0x7FFFu + ((x.u >> 16) & 1u);
  return (bhalf)(r >> 16);
}
__device__ __forceinline__ float b2f(bhalf h){
  union{ unsigned u; float f; } x; x.u = ((unsigned)h) << 16;
  return x.f;
}

// ---------------------------------------------------------------------------
// f32 -> bf16 conversion (optionally fused ReLU), float4-vectorized.
// ---------------------------------------------------------------------------
template<bool RELU>
__global__ __launch_bounds__(256) void conv_x(
    const float* __restrict__ X, bhalf* __restrict__ Xb, int n4)
{
  int i = blockIdx.x * 256 + threadIdx.x;
  if (i < n4){
    float4 v = ((const float4*)X)[i];
    if (RELU){
      v.x = fmaxf(v.x, 0.f); v.y = fmaxf(v.y, 0.f);
      v.z = fmaxf(v.z, 0.f); v.w = fmaxf(v.w, 0.f);
    }
    ushort4 o;
    o.x = f2b(v.x); o.y = f2b(v.y); o.z = f2b(v.z); o.w = f2b(v.w);
    ((ushort4*)Xb)[i] = o;
  }
}

// Convert 4 weight matrices (128x128 f32 each) into contiguous bf16 [4][16384].
__global__ __launch_bounds__(256) void conv_w4(
    const float* __restrict__ w0, const float* __restrict__ w1,
    const float* __restrict__ w2, const float* __restrict__ w3,
    bhalf* __restrict__ dst)
{
  int i = blockIdx.x * 256 + threadIdx.x;   // < 4*16384
  int sel = i >> 14, off = i & 16383;
  const float* s = (sel == 0) ? w0 : (sel == 1) ? w1 : (sel == 2) ? w2 : w3;
  dst[i] = f2b(s[off]);
}

// ---------------------------------------------------------------------------
// MFMA GEMM v3: W staged in LDS (padded rows), A-frags in registers.
// 4 waves/block; wave w owns rows row0+w*16..+15, all 128 cols.
// LDS row pitch = 136 bhalf (272 B = 17 x 16B): B-frag ds_read_b128 at
// byte row*272 + ks*64 + lb*16 -> lanes (la,lb) hit bank (4*la+4*lb)%32,
// worst 2-way (free, m136). Staging: 32 KB once per block.
// Fragment mapping (m89/m92-verified): A lane l: row=l&15, k-octet=l>>4;
// B: col=l&15 (W is [out][in] = B^T); C/D: col=l&15, row=(l>>4)*4+reg.
// ---------------------------------------------------------------------------
__global__ __launch_bounds__(256) void gemm_mfma(
    const bhalf* __restrict__ Xb, const bhalf* __restrict__ Wb4,
    const float* __restrict__ bk, const float* __restrict__ bq,
    const float* __restrict__ bv, const float* __restrict__ bs,
    float* __restrict__ Ko, bhalf* __restrict__ Qb,
    bhalf* __restrict__ Vb, float* __restrict__ So, int n)
{
  __shared__ bhalf sW[128 * 136];   // 34.8 KB

  const int m = blockIdx.x & 3;
  const bhalf* W = Wb4 + m * (HH * HH);
  const float* B = (m == 0) ? bk : (m == 1) ? bq : (m == 2) ? bv : bs;

  const int tid = threadIdx.x;

  // ---- stage W into LDS: 128 rows x 16 chunks of 8 bhalf (16B) ----
  for (int fi = tid; fi < 128 * 16; fi += 256){
    int r = fi >> 4, c8 = fi & 15;
    *(bf16x8*)&sW[r * 136 + c8 * 8] = *(const bf16x8*)(W + r * HH + c8 * 8);
  }

  const int wv   = tid >> 6;
  const int lane = tid & 63;
  const int row0 = (blockIdx.x >> 2) * 64 + wv * 16;
  const int la = lane & 15;       // A-row / B-col within tile
  const int lb = lane >> 4;       // k-octet selector

  // A-frags from global (each lane owns one X row slice), 16 VGPR
  const bhalf* ap = Xb + (size_t)(row0 + la) * HH + lb * 8;
  bf16x8 a[4];
#pragma unroll
  for (int ks = 0; ks < 4; ++ks) a[ks] = *(const bf16x8*)(ap + ks * 32);

  __syncthreads();

  f32x4 acc[8];
#pragma unroll
  for (int ct = 0; ct < 8; ++ct) acc[ct] = (f32x4){0.f, 0.f, 0.f, 0.f};

#pragma unroll
  for (int ks = 0; ks < 4; ++ks){
#pragma unroll
    for (int ct = 0; ct < 8; ++ct){
      bf16x8 b = *(const bf16x8*)&sW[(ct * 16 + la) * 136 + ks * 32 + lb * 8];
      acc[ct] = __builtin_amdgcn_mfma_f32_16x16x32_bf16(a[ks], b, acc[ct], 0, 0, 0);
    }
  }

  const int r0 = lb * 4;
  if (m == 0 || m == 3){
    float* D = (m == 0) ? Ko : So;
#pragma unroll
    for (int ct = 0; ct < 8; ++ct){
      int col = ct * 16 + la;
      float bb = B[col];
#pragma unroll
      for (int r = 0; r < 4; ++r){
        int gr = row0 + r0 + r;
        if (gr < n) D[(size_t)gr * HH + col] = acc[ct][r] + bb;
      }
    }
  } else {
    bhalf* Db = (m == 1) ? Qb : Vb;
#pragma unroll
    for (int ct = 0; ct < 8; ++ct){
      int col = ct * 16 + la;
      float bb = B[col];
#pragma unroll
      for (int r = 0; r < 4; ++r){
        int gr = row0 + r0 + r;
        if (gr < n) Db[(size_t)gr * HH + col] = f2b(acc[ct][r] + bb);
      }
    }
  }
}

// ---------------------------------------------------------------------------
// CSR build
// ---------------------------------------------------------------------------
__global__ void zero_int(int* __restrict__ p, int n){
  int i = blockIdx.x * blockDim.x + threadIdx.x;
  if (i < n) p[i] = 0;
}

__global__ void hist_dst(const int* __restrict__ ei, int E, int* __restrict__ cnt){
  int e = blockIdx.x * blockDim.x + threadIdx.x;
  if (e < E) atomicAdd(&cnt[ei[E + e]], 1);
}

__global__ __launch_bounds__(256) void scan1(const int* __restrict__ cnt, int n,
                                             int* __restrict__ excl, int* __restrict__ bsum){
  __shared__ int s[256];
  int t = threadIdx.x;
  int i = blockIdx.x * 256 + t;
  int v = (i < n) ? cnt[i] : 0;
  s[t] = v;
  __syncthreads();
  for (int off = 1; off < 256; off <<= 1){
    int u = (t >= off) ? s[t - off] : 0;
    __syncthreads();
    s[t] += u;
    __syncthreads();
  }
  if (i < n) excl[i] = s[t] - v;
  if (t == 255) bsum[blockIdx.x] = s[255];
}

__global__ __launch_bounds__(256) void scan2(int* __restrict__ bsum, int nb){
  __shared__ int s[256];
  int t = threadIdx.x;
  int v = (t < nb) ? bsum[t] : 0;
  s[t] = v;
  __syncthreads();
  for (int off = 1; off < 256; off <<= 1){
    int u = (t >= off) ? s[t - off] : 0;
    __syncthreads();
    s[t] += u;
    __syncthreads();
  }
  if (t < nb) bsum[t] = s[t] - v;
}

__global__ void scan3(int* __restrict__ row_start, const int* __restrict__ bsum,
                      int n, int E, int* __restrict__ cursor){
  int i = blockIdx.x * blockDim.x + threadIdx.x;
  if (i < n){
    int v = row_start[i] + bsum[i >> 8];
    row_start[i] = v;
    cursor[i] = v;
  }
  if (i == n) row_start[n] = E;
}

__global__ void scatter_src(const int* __restrict__ ei, int E,
                            int* __restrict__ cursor, int* __restrict__ csr_src){
  int e = blockIdx.x * blockDim.x + threadIdx.x;
  if (e < E){
    int d = ei[E + e];
    int pos = atomicAdd(&cursor[d], 1);
    csr_src[pos] = ei[e];
  }
}

// ---------------------------------------------------------------------------
// Node-centric aggregate: one wave per dst node, 2 feats per lane.
// Q/V gathers bf16 (ushort2 per lane) -> half traffic.
// ---------------------------------------------------------------------------
__global__ __launch_bounds__(256) void node_agg(
    const float* __restrict__ Kx, const bhalf* __restrict__ Qb,
    const bhalf* __restrict__ Vb, const float* __restrict__ Sx,
    const int* __restrict__ row_start, const int* __restrict__ csr_src,
    int n, float* __restrict__ H)
{
  int w = blockIdx.x * 4 + (threadIdx.x >> 6);
  w = __builtin_amdgcn_readfirstlane(w);
  if (w >= n) return;
  int lane = threadIdx.x & 63;

  float2 kd = ((const float2*)(Kx + (size_t)w * HH))[lane];
  float ax = 0.f, ay = 0.f;
  int j = row_start[w];
  const int jend = row_start[w + 1];

  for (; j + 3 < jend; j += 4){
    int s0 = csr_src[j],     s1 = csr_src[j + 1];
    int s2 = csr_src[j + 2], s3 = csr_src[j + 3];
    ushort2 q0 = ((const ushort2*)(Qb + (size_t)s0 * HH))[lane];
    ushort2 v0 = ((const ushort2*)(Vb + (size_t)s0 * HH))[lane];
    ushort2 q1 = ((const ushort2*)(Qb + (size_t)s1 * HH))[lane];
    ushort2 v1 = ((const ushort2*)(Vb + (size_t)s1 * HH))[lane];
    ushort2 q2 = ((const ushort2*)(Qb + (size_t)s2 * HH))[lane];
    ushort2 v2 = ((const ushort2*)(Vb + (size_t)s2 * HH))[lane];
    ushort2 q3 = ((const ushort2*)(Qb + (size_t)s3 * HH))[lane];
    ushort2 v3 = ((const ushort2*)(Vb + (size_t)s3 * HH))[lane];
    ax = fmaf(sigf(kd.x + b2f(q0.x)), b2f(v0.x), ax);
    ay = fmaf(sigf(kd.y + b2f(q0.y)), b2f(v0.y), ay);
    ax = fmaf(sigf(kd.x + b2f(q1.x)), b2f(v1.x), ax);
    ay = fmaf(sigf(kd.y + b2f(q1.y)), b2f(v1.y), ay);
    ax = fmaf(sigf(kd.x + b2f(q2.x)), b2f(v2.x), ax);
    ay = fmaf(sigf(kd.y + b2f(q2.y)), b2f(v2.y), ay);
    ax = fmaf(sigf(kd.x + b2f(q3.x)), b2f(v3.x), ax);
    ay = fmaf(sigf(kd.y + b2f(q3.y)), b2f(v3.y), ay);
  }
  for (; j < jend; ++j){
    int sA = csr_src[j];
    ushort2 qa = ((const ushort2*)(Qb + (size_t)sA * HH))[lane];
    ushort2 va = ((const ushort2*)(Vb + (size_t)sA * HH))[lane];
    ax = fmaf(sigf(kd.x + b2f(qa.x)), b2f(va.x), ax);
    ay = fmaf(sigf(kd.y + b2f(qa.y)), b2f(va.y), ay);
  }
  float2 sk = ((const float2*)(Sx + (size_t)w * HH))[lane];
  float2 o; o.x = ax + sk.x; o.y = ay + sk.y;
  ((float2*)(H + (size_t)w * HH))[lane] = o;
}

// ---------------------------------------------------------------------------
// Pool, two-phase.
// ---------------------------------------------------------------------------
__global__ __launch_bounds__(256) void pool_partial(
    const float* __restrict__ Hn, const int* __restrict__ batch,
    int n, float* __restrict__ pmax, float* __restrict__ psum)
{
  int g = blockIdx.x;
  int s = blockIdx.y;
  int lo = 0, hi = n;
  while (lo < hi){ int mid = (lo + hi) >> 1; if (batch[mid] < g) lo = mid + 1; else hi = mid; }
  int s0 = lo;
  lo = s0; hi = n;
  while (lo < hi){ int mid = (lo + hi) >> 1; if (batch[mid] < g + 1) lo = mid + 1; else hi = mid; }
  int e0 = lo;

  int len = e0 - s0;
  int a0 = s0 + (int)(((long long)len * s) / PS);
  int a1 = s0 + (int)(((long long)len * (s + 1)) / PS);

  int t = threadIdx.x;
  int f = t & 127;
  int half = t >> 7;
  float mx = -INFINITY;
  float sm = 0.f;
  for (int i = a0 + half; i < a1; i += 2){
    float v = Hn[(size_t)i * HH + f];
    mx = fmaxf(mx, v);
    sm += v;
  }
  __shared__ float smx[256], ssm[256];
  smx[t] = mx; ssm[t] = sm;
  __syncthreads();
  if (half == 0){
    mx = fmaxf(mx, smx[t + 128]);
    sm += ssm[t + 128];
    size_t o = ((size_t)g * PS + s) * 128 + f;
    pmax[o] = mx;
    psum[o] = sm;
  }
}

__global__ __launch_bounds__(128) void pool_reduce(
    const float* __restrict__ pmax, const float* __restrict__ psum,
    const int* __restrict__ batch, int n, float* __restrict__ Fp)
{
  int g = blockIdx.x;
  int f = threadIdx.x;
  int lo = 0, hi = n;
  while (lo < hi){ int mid = (lo + hi) >> 1; if (batch[mid] < g) lo = mid + 1; else hi = mid; }
  int s0 = lo;
  lo = s0; hi = n;
  while (lo < hi){ int mid = (lo + hi) >> 1; if (batch[mid] < g + 1) lo = mid + 1; else hi = mid; }
  int cnt = lo - s0;

  float mx = -INFINITY, sm = 0.f;
#pragma unroll
  for (int s = 0; s < PS; ++s){
    size_t o = ((size_t)g * PS + s) * 128 + f;
    mx = fmaxf(mx, pmax[o]);
    sm += psum[o];
  }
  float mean = sm / fmaxf((float)cnt, 1.0f);
  Fp[(size_t)g * 256 + f]       = mx;
  Fp[(size_t)g * 256 + 128 + f] = mean;
}

// ---------------------------------------------------------------------------
// MLP head (parallel)
// ---------------------------------------------------------------------------
__global__ __launch_bounds__(256) void head_gemm1(
    const float* __restrict__ Fp, const float* __restrict__ W1,
    const float* __restrict__ b1, float* __restrict__ A1)
{
  int idx = blockIdx.x * 256 + threadIdx.x;
  int r = idx >> 7, c = idx & 127;
  const float4* f4 = (const float4*)(Fp + r * 256);
  const float4* w4 = (const float4*)(W1 + c * 256);
  float acc = b1[c];
#pragma unroll
  for (int k = 0; k < 64; ++k) acc += dot4(f4[k], w4[k]);
  A1[idx] = acc;
}

__global__ __launch_bounds__(256) void head_bn_relu1(
    const float* __restrict__ A1, const float* __restrict__ g1,
    const float* __restrict__ be1, float* __restrict__ H1n)
{
  __shared__ float sMS[256];
  int t = threadIdx.x;
  if (t < 128){
    float m = 0.f, m2 = 0.f;
    for (int r = 0; r < 64; ++r){ float v = A1[r * 128 + t]; m += v; m2 += v * v; }
    m *= (1.f / 64.f); m2 *= (1.f / 64.f);
    float var = m2 - m * m;
    sMS[t] = m;
    sMS[128 + t] = g1[t] * rsqrtf(var + 1e-5f);
  }
  __syncthreads();
  for (int i = t; i < 64 * 128; i += 256){
    int c = i & 127;
    float v = (A1[i] - sMS[c]) * sMS[128 + c] + be1[c];
    H1n[i] = fmaxf(v, 0.f);
  }
}

__global__ __launch_bounds__(256) void head_gemm2(
    const float* __restrict__ H1n, const float* __restrict__ W2,
    const float* __restrict__ b2, float* __restrict__ A2)
{
  int idx = blockIdx.x * 256 + threadIdx.x;
  int r = idx >> 6, c = idx & 63;
  const float4* f4 = (const float4*)(H1n + r * 128);
  const float4* w4 = (const float4*)(W2 + c * 128);
  float acc = b2[c];
#pragma unroll
  for (int k = 0; k < 32; ++k) acc += dot4(f4[k], w4[k]);
  A2[idx] = acc;
}

__global__ __launch_bounds__(256) void head_tail(
    const float* __restrict__ A2, const float* __restrict__ g2,
    const float* __restrict__ be2, const float* __restrict__ W3,
    const float* __restrict__ b3, float* __restrict__ out)
{
  __shared__ float sH[64 * 64];
  __shared__ float sMS[128];
  int t = threadIdx.x;
  for (int i = t; i < 64 * 64 / 4; i += 256)
    ((float4*)sH)[i] = ((const float4*)A2)[i];
  __syncthreads();
  if (t < 64){
    float m = 0.f, m2 = 0.f;
    for (int r = 0; r < 64; ++r){ float v = sH[r * 64 + t]; m += v; m2 += v * v; }
    m *= (1.f / 64.f); m2 *= (1.f / 64.f);
    float var = m2 - m * m;
    sMS[t] = m;
    sMS[64 + t] = g2[t] * rsqrtf(var + 1e-5f);
  }
  __syncthreads();
  for (int i = t; i < 64 * 64; i += 256){
    int c = i & 63;
    float v = (sH[i] - sMS[c]) * sMS[64 + c] + be2[c];
    sH[i] = fmaxf(v, 0.f);
  }
  __syncthreads();
  if (t < 64){
    float acc = b3[0];
#pragma unroll
    for (int k = 0; k < 64; ++k) acc += sH[t * 64 + k] * W3[k];
    out[t] = acc;
  }
}

// ---------------------------------------------------------------------------
extern "C" void kernel_launch(void* const* d_in, const int* in_sizes, int n_in,
                              void* d_out, int out_size, void* d_ws, size_t ws_size,
                              hipStream_t stream)
{
  const float* x     = (const float*)d_in[0];
  const int*   ei    = (const int*)d_in[1];
  const int*   batch = (const int*)d_in[2];

  const float* l0Wk = (const float*)d_in[3];  const float* l0bk = (const float*)d_in[4];
  const float* l0Wq = (const float*)d_in[5];  const float* l0bq = (const float*)d_in[6];
  const float* l0Wv = (const float*)d_in[7];  const float* l0bv = (const float*)d_in[8];
  const float* l0Ws = (const float*)d_in[9];  const float* l0bs = (const float*)d_in[10];
  const float* l1Wk = (const float*)d_in[11]; const float* l1bk = (const float*)d_in[12];
  const float* l1Wq = (const float*)d_in[13]; const float* l1bq = (const float*)d_in[14];
  const float* l1Wv = (const float*)d_in[15]; const float* l1bv = (const float*)d_in[16];
  const float* l1Ws = (const float*)d_in[17]; const float* l1bs = (const float*)d_in[18];

  const float* W1  = (const float*)d_in[19]; const float* b1  = (const float*)d_in[20];
  const float* g1  = (const float*)d_in[21]; const float* be1 = (const float*)d_in[22];
  const float* W2  = (const float*)d_in[23]; const float* b2  = (const float*)d_in[24];
  const float* g2  = (const float*)d_in[25]; const float* be2 = (const float*)d_in[26];
  const float* W3  = (const float*)d_in[27]; const float* b3  = (const float*)d_in[28];

  const int N = in_sizes[0] / HH;
  const int E = in_sizes[1] / 2;
  const int G = out_size;
  const size_t NH = (size_t)N * HH;

  float* ws = (float*)d_ws;
  float* K  = ws;                               // NH f32
  float* H0 = K + NH;                           // NH f32
  float* H1 = H0 + NH;                          // NH f32
  float* Fp = H1 + NH;                          // G*256
  float* A1  = Fp + (size_t)G * 256;            // 64*128
  float* H1n = A1 + 64 * 128;
  float* A2  = H1n + 64 * 128;                  // 64*64
  float* pmax = A2 + 64 * 64;                   // G*PS*128
  float* psum = pmax + (size_t)G * PS * 128;    // G*PS*128
  bhalf* Qb  = (bhalf*)(psum + (size_t)G * PS * 128);  // NH bf16
  bhalf* Vb  = Qb + NH;                                // NH bf16
  bhalf* Xb  = Vb + NH;                                // NH bf16
  bhalf* Wb0 = Xb + NH;                                // 4*16384 bf16
  bhalf* Wb1 = Wb0 + 4 * HH * HH;                      // 4*16384 bf16
  int* ip        = (int*)(Wb1 + 4 * HH * HH);
  int* row_start = ip;                 // N+1
  int* cursor    = row_start + (N + 1);
  int* cnt       = cursor + N;
  int* csr_src   = cnt + N;            // E
  int* bsum      = csr_src + E;        // 256

  const int nb   = (N + 255) / 256;
  const int ebl  = (E + 255) / 256;
  const int conv_blocks = (int)((NH / 4 + 255) / 256);
  const int gemm_blocks = ((N + 63) / 64) * 4;   // 4 matrices interleaved
  const int agg_blocks = (N + 3) / 4;

  // --- CSR build ---
  zero_int<<<nb, 256, 0, stream>>>(cnt, N);
  hist_dst<<<ebl, 256, 0, stream>>>(ei, E, cnt);
  scan1<<<nb, 256, 0, stream>>>(cnt, N, row_start, bsum);
  scan2<<<1, 256, 0, stream>>>(bsum, nb);
  scan3<<<(N + 256) / 256, 256, 0, stream>>>(row_start, bsum, N, E, cursor);
  scatter_src<<<ebl, 256, 0, stream>>>(ei, E, cursor, csr_src);

  // --- weight conversions (tiny) ---
  conv_w4<<<(4 * HH * HH) / 256, 256, 0, stream>>>(l0Wk, l0Wq, l0Wv, l0Ws, Wb0);
  conv_w4<<<(4 * HH * HH) / 256, 256, 0, stream>>>(l1Wk, l1Wq, l1Wv, l1Ws, Wb1);

  // --- Layer 0 ---
  conv_x<false><<<conv_blocks, 256, 0, stream>>>(x, Xb, (int)(NH / 4));
  gemm_mfma<<<gemm_blocks, 256, 0, stream>>>(
      Xb, Wb0, l0bk, l0bq, l0bv, l0bs, K, Qb, Vb, H0, N);
  node_agg<<<agg_blocks, 256, 0, stream>>>(K, Qb, Vb, H0, row_start, csr_src, N, H0);

  // --- Layer 1 (ReLU folded into conversion) ---
  conv_x<true><<<conv_blocks, 256, 0, stream>>>(H0, Xb, (int)(NH / 4));
  gemm_mfma<<<gemm_blocks, 256, 0, stream>>>(
      Xb, Wb1, l1bk, l1bq, l1bv, l1bs, K, Qb, Vb, H1, N);
  node_agg<<<agg_blocks, 256, 0, stream>>>(K, Qb, Vb, H1, row_start, csr_src, N, H1);

  // --- Pool (two-phase) + head ---
  pool_partial<<<dim3(G, PS), 256, 0, stream>>>(H1, batch, N, pmax, psum);
  pool_reduce<<<G, 128, 0, stream>>>(pmax, psum, batch, N, Fp);
  head_gemm1<<<32, 256, 0, stream>>>(Fp, W1, b1, A1);
  head_bn_relu1<<<1, 256, 0, stream>>>(A1, g1, be1, H1n);
  head_gemm2<<<16, 256, 0, stream>>>(H1n, W2, b2, A2);
  head_tail<<<1, 256, 0, stream>>>(A2, g2, be2, W3, b3, (float*)d_out);
}